// Round 16
// baseline (646.734 us; speedup 1.0000x reference)
//
#include <hip/hip_runtime.h>
#include <hip/hip_fp16.h>

#define NUMS   128
#define NVARS  16
#define BATCH  8192
#define ITERS  15

// d_out element offsets (return order: cv, cp, cr, acc_fixed, acc_primal, primal_stack, fixed_stack)
#define OUT_ACCF (3*BATCH*NVARS)           // 393216
#define OUT_ACCP (OUT_ACCF + BATCH)        // 401408
#define OUT_PST  (OUT_ACCP + BATCH)        // 409600
#define OUT_FST  (OUT_PST + ITERS*BATCH)   // 532480

// ---------------------------------------------------------------------------
// prep: AtA = 2(P^T P + Pd^T Pd + Pdd^T Pdd); cost_mat = [[I+AtA, Aeq^T],[Aeq,0]];
// M = inv(cost_mat) via f64 Gauss-Jordan. ws: [0,324) M row-major f32,
// [324,596) AtA padded [16][17] f32.  (R11 layout)
// ---------------------------------------------------------------------------
__global__ void prep_kernel(const float* __restrict__ P, const float* __restrict__ Pd,
                            const float* __restrict__ Pdd, float* __restrict__ ws)
{
    __shared__ double GA[18][36];
    __shared__ float  ata[16][16];
    __shared__ double piv_s;
    const int t = threadIdx.x;

    if (t < 256) {
        int j = t >> 4, k = t & 15;
        float s = 0.f;
        for (int i = 0; i < NUMS; ++i)
            s += P[i*16+j]*P[i*16+k] + Pd[i*16+j]*Pd[i*16+k] + Pdd[i*16+j]*Pdd[i*16+k];
        ata[j][k] = 2.f * s;
    }
    __syncthreads();

    const int gi = t / 36, gj = t % 36;   // blockDim = 648
    {
        double v;
        if (gj < 18) {
            if (gi < 16 && gj < 16)      v = (gi == gj ? 1.0 : 0.0) + (double)ata[gi][gj];
            else if (gi < 16)            v = (gj == 16) ? (double)P[gi] : (double)Pd[gi];
            else if (gj < 16)            v = (gi == 16) ? (double)P[gj] : (double)Pd[gj];
            else                         v = 0.0;
        } else {
            v = ((gj - 18) == gi) ? 1.0 : 0.0;
        }
        GA[gi][gj] = v;
    }
    __syncthreads();

    for (int k = 0; k < 18; ++k) {
        if (t == 0) piv_s = GA[k][k];
        __syncthreads();
        if (gi == k) GA[gi][gj] /= piv_s;
        __syncthreads();
        double f  = GA[gi][k];
        double rk = GA[k][gj];
        __syncthreads();
        if (gi != k) GA[gi][gj] -= f * rk;
        __syncthreads();
    }

    if (gj >= 18) ws[gi*18 + (gj - 18)] = (float)GA[gi][gj];
    if (t < 256)  ws[324 + (t >> 4)*17 + (t & 15)] = ata[t >> 4][t & 15];
    if (t >= 256 && t < 272) ws[324 + (t - 256)*17 + 16] = 0.f;
}

// reduce-scatter of a 16-vector across 16 lanes: lane l returns sum over lanes
// of component l. 4 halving stages, static indexing (verified R11).
__device__ __forceinline__ float reduce_scatter16(const float (&pjp)[16], int l)
{
    float v8[8];
#pragma unroll
    for (int k = 0; k < 8; ++k) {
        float send = (l & 8) ? pjp[k] : pjp[k+8];
        float keep = (l & 8) ? pjp[k+8] : pjp[k];
        v8[k] = keep + __shfl_xor(send, 8, 16);
    }
    float v4[4];
#pragma unroll
    for (int k = 0; k < 4; ++k) {
        float send = (l & 4) ? v8[k] : v8[k+4];
        float keep = (l & 4) ? v8[k+4] : v8[k];
        v4[k] = keep + __shfl_xor(send, 4, 16);
    }
    float v2[2];
#pragma unroll
    for (int k = 0; k < 2; ++k) {
        float send = (l & 2) ? v4[k] : v4[k+2];
        float keep = (l & 2) ? v4[k+2] : v4[k];
        v2[k] = keep + __shfl_xor(send, 2, 16);
    }
    float send = (l & 1) ? v2[0] : v2[1];
    float keep = (l & 1) ? v2[1] : v2[0];
    return keep + __shfl_xor(send, 1, 16);
}

__device__ __forceinline__ __half2 u2h(unsigned int u) {
    __half2 h;
    __builtin_memcpy(&h, &u, 4);
    return h;
}

// ---------------------------------------------------------------------------
// main solver: R11 structure, matvec passes in PACKED F16 (v_pk_fma_f16).
// R15 lesson: bf16 halved DS (96 b128/wave/iter) but the per-element unpack
// (+768 VALU) cost more than the DS relief -> 581us vs R11's 455us. Packed
// f16 keeps the halved DS AND halves matvec VALU (384 hfma2 vs 768 f32 fma),
// no unpack. f16 (11-bit mantissa) is 8x finer than bf16 which passed at
// absmax 16. Accumulate un/pjp in half2; convert at pass boundaries.
// Projection/residuals/KKT/cq/reductions stay f32. cs reads hoisted: 16 per
// iteration (cj2 precomputed) instead of 48.
// ---------------------------------------------------------------------------
__launch_bounds__(192, 1)
__global__ void solve_kernel(
    const float* __restrict__ P,    const float* __restrict__ Pd,   const float* __restrict__ Pdd,
    const float* __restrict__ lamv, const float* __restrict__ lamp, const float* __restrict__ lamr,
    const float* __restrict__ cinv, const float* __restrict__ cinp, const float* __restrict__ cinr,
    const float* __restrict__ beqv, const float* __restrict__ beqp, const float* __restrict__ beqr,
    const float* __restrict__ c0v,  const float* __restrict__ c0p,  const float* __restrict__ c0r,
    float* __restrict__ out, const float* __restrict__ ws)
{
    __shared__ __align__(16) __half Ptb[3][16][128]; // f16 A^T: Ptb[m][j][i]
    __shared__ float Ml[16][19];                     // M rows 0..15, cols 0..17 (pad 19)
    __shared__ float ata[16][17];
    __shared__ float cs[12][17];                     // per-unit c (broadcast reads)
    __shared__ float res_st[ITERS][12];
    __shared__ float fix_st[ITERS][12];

    // ---- stage constants (f32 -> f16 RN for Ptb) ----
#pragma unroll
    for (int m = 0; m < 3; ++m) {
        const float* src = (m == 0) ? P : (m == 1) ? Pd : Pdd;
        for (int f = threadIdx.x; f < 2048; f += 192) {
            int j = f >> 7, i = f & 127;
            Ptb[m][j][i] = __float2half_rn(src[i*16 + j]);
        }
    }
    for (int f = threadIdx.x; f < 288; f += 192) Ml[f / 18][f % 18] = ws[f];
    for (int f = threadIdx.x; f < 272; f += 192) ata[f / 17][f % 17] = ws[324 + f];
    __syncthreads();

    const int g  = threadIdx.x >> 4;   // group 0..11
    const int l  = threadIdx.x & 15;   // lane-in-group
    const int rl = g / 3;              // local row 0..3
    const int ch = g - rl * 3;         // channel 0..2
    const int row = blockIdx.x * 4 + rl;

    const float* lam_p = (ch == 0) ? lamv : (ch == 1) ? lamp : lamr;
    const float* cin_p = (ch == 0) ? cinv : (ch == 1) ? cinp : cinr;
    const float* beq_p = (ch == 0) ? beqv : (ch == 1) ? beqp : beqr;
    const float* c0_p  = (ch == 0) ? c0v  : (ch == 1) ? c0p  : c0r;

    // bounds per (ch, m)
    float bmax[3], bmin[3];
    bmax[0] = (ch == 0) ? 20.f : (ch == 1) ? 0.2f  : 0.25f;
    bmin[0] = (ch == 0) ? 12.f : (ch == 1) ? -0.2f : -0.25f;
    bmax[1] = (ch == 0) ? 3.f  : 0.25f;
    bmin[1] = (ch == 0) ? -3.f : -0.25f;
    bmax[2] = (ch == 0) ? 3.f  : 0.15f;
    bmin[2] = (ch == 0) ? -3.f : -0.15f;

    // ---- distributed per-unit state: lane l owns component l ----
    float c_l  = c0_p[row * 16 + l];
    float L_l  = lam_p[row * 16 + l] + cin_p[row * 16 + l];
    float pj_l, cq_l;
    const float beq0 = beq_p[row * 2];
    const float beq1 = beq_p[row * 2 + 1];
    float uo[3][8];                    // lane's 8 constraint rows (8l..8l+7) per m

    cs[g][l] = c_l;

    // ---- init pass: uo, pjp0 -> reduce-scatter -> pj_l; cq0 ----
    {
        __half2 cj2[16];
#pragma unroll
        for (int j = 0; j < 16; ++j) cj2[j] = __float2half2_rn(cs[g][j]);

        __half2 acc2[16];
#pragma unroll
        for (int j = 0; j < 16; ++j) acc2[j] = __float2half2_rn(0.f);

#pragma unroll
        for (int m = 0; m < 3; ++m) {
            __half2 un2[4];
#pragma unroll
            for (int k = 0; k < 4; ++k) un2[k] = __float2half2_rn(0.f);
#pragma unroll 4
            for (int j = 0; j < 16; ++j) {
                uint4 q = *(const uint4*)&Ptb[m][j][8*l];
                un2[0] = __hfma2(cj2[j], u2h(q.x), un2[0]);
                un2[1] = __hfma2(cj2[j], u2h(q.y), un2[1]);
                un2[2] = __hfma2(cj2[j], u2h(q.z), un2[2]);
                un2[3] = __hfma2(cj2[j], u2h(q.w), un2[3]);
            }
            float un[8];
#pragma unroll
            for (int k = 0; k < 4; ++k) {
                un[2*k]   = __low2float(un2[k]);
                un[2*k+1] = __high2float(un2[k]);
            }
            float h[8];
#pragma unroll
            for (int k = 0; k < 8; ++k) {
                float x = un[k] - bmax[m];
                float rvp = fmaxf(x, 0.f);
                float y = un[k] - bmin[m];
                float rvm = fmaxf(-y, 0.f);
                h[k] = rvp - rvm;
                uo[m][k] = un[k];
            }
            __half2 h2[4];
#pragma unroll
            for (int k = 0; k < 4; ++k) h2[k] = __floats2half2_rn(h[2*k], h[2*k+1]);
#pragma unroll 4
            for (int j = 0; j < 16; ++j) {
                uint4 q = *(const uint4*)&Ptb[m][j][8*l];
                acc2[j] = __hfma2(h2[0], u2h(q.x), acc2[j]);
                acc2[j] = __hfma2(h2[1], u2h(q.y), acc2[j]);
                acc2[j] = __hfma2(h2[2], u2h(q.z), acc2[j]);
                acc2[j] = __hfma2(h2[3], u2h(q.w), acc2[j]);
            }
        }
        float pjp[16];
#pragma unroll
        for (int j = 0; j < 16; ++j)
            pjp[j] = __low2float(acc2[j]) + __high2float(acc2[j]);
        pj_l = reduce_scatter16(pjp, l);

        float cqd = 0.f;
#pragma unroll
        for (int k = 0; k < 16; ++k) cqd += ata[l][k] * cs[g][k];
        cq_l = cqd;
    }

    // ---- 15 ADMM iterations ----
    for (int t = 0; t < ITERS; ++t) {
        // KKT solve: rhs_k = L_k + cq_k - pj_k; lane l owns M row l
        float r_l = L_l + cq_l - pj_l;
        float sj = Ml[l][16] * beq0 + Ml[l][17] * beq1;
#pragma unroll
        for (int k = 0; k < 16; ++k) sj += Ml[l][k] * __shfl(r_l, k, 16);

        float d = sj - c_l;
        float cdel2 = d * d;
        c_l = sj;
        cs[g][l] = c_l;

        // precompute duplicated-f16 c broadcast (16 LDS reads, shared by 3 m)
        __half2 cj2[16];
#pragma unroll
        for (int j = 0; j < 16; ++j) cj2[j] = __float2half2_rn(cs[g][j]);

        // fused Ax + projection + pjp accumulation (packed f16 matvecs)
        float res2 = 0.f, ds2 = 0.f;
        __half2 acc2[16];
#pragma unroll
        for (int j = 0; j < 16; ++j) acc2[j] = __float2half2_rn(0.f);

#pragma unroll
        for (int m = 0; m < 3; ++m) {
            __half2 un2[4];
#pragma unroll
            for (int k = 0; k < 4; ++k) un2[k] = __float2half2_rn(0.f);
#pragma unroll 4
            for (int j = 0; j < 16; ++j) {
                uint4 q = *(const uint4*)&Ptb[m][j][8*l];
                un2[0] = __hfma2(cj2[j], u2h(q.x), un2[0]);
                un2[1] = __hfma2(cj2[j], u2h(q.y), un2[1]);
                un2[2] = __hfma2(cj2[j], u2h(q.z), un2[2]);
                un2[3] = __hfma2(cj2[j], u2h(q.w), un2[3]);
            }
            float un[8];
#pragma unroll
            for (int k = 0; k < 4; ++k) {
                un[2*k]   = __low2float(un2[k]);
                un[2*k+1] = __high2float(un2[k]);
            }
            float h[8];
#pragma unroll
            for (int k = 0; k < 8; ++k) {
                float x   = un[k] - bmax[m];
                float rvp = fmaxf(x, 0.f);        // relu(Ax - bmax)
                float spn = rvp - x;              // new s+
                float y   = un[k] - bmin[m];
                float smn = fmaxf(y, 0.f);        // new s-
                float rvm = smn - y;              // relu(bmin - Ax)
                res2 += rvp * rvp + rvm * rvm;
                h[k] = rvp - rvm;
                float xo  = uo[m][k] - bmax[m];
                float spo = fmaxf(-xo, 0.f);      // old s+
                float yo  = uo[m][k] - bmin[m];
                float smo = fmaxf(yo, 0.f);       // old s-
                float e1 = spn - spo;
                float e2 = smn - smo;
                ds2 += e1 * e1 + e2 * e2;
                uo[m][k] = un[k];
            }
            __half2 h2[4];
#pragma unroll
            for (int k = 0; k < 4; ++k) h2[k] = __floats2half2_rn(h[2*k], h[2*k+1]);
#pragma unroll 4
            for (int j = 0; j < 16; ++j) {
                uint4 q = *(const uint4*)&Ptb[m][j][8*l];
                acc2[j] = __hfma2(h2[0], u2h(q.x), acc2[j]);
                acc2[j] = __hfma2(h2[1], u2h(q.y), acc2[j]);
                acc2[j] = __hfma2(h2[2], u2h(q.z), acc2[j]);
                acc2[j] = __hfma2(h2[3], u2h(q.w), acc2[j]);
            }
        }

        float pjp[16];
#pragma unroll
        for (int j = 0; j < 16; ++j)
            pjp[j] = __low2float(acc2[j]) + __high2float(acc2[j]);
        pj_l = reduce_scatter16(pjp, l);

        // cq for next solve (independent of projection -> scheduler overlap)
        float cqd = 0.f;
#pragma unroll
        for (int k = 0; k < 16; ++k) cqd += ata[l][k] * cs[g][k];
        cq_l = cqd;

        // butterfly 4 scalars across the 16 lanes (pj2 = ||lam_new-lam_old||^2)
        float pj2 = pj_l * pj_l;
#pragma unroll
        for (int s = 1; s < 16; s <<= 1) {
            res2  += __shfl_xor(res2,  s, 16);
            ds2   += __shfl_xor(ds2,   s, 16);
            cdel2 += __shfl_xor(cdel2, s, 16);
            pj2   += __shfl_xor(pj2,   s, 16);
        }

        L_l -= pj_l;

        if (l == 0) {
            res_st[t][g] = sqrtf(res2);
            fix_st[t][g] = sqrtf(pj2) + sqrtf(ds2) + sqrtf(cdel2);
        }
    }

    // ---- outputs ----
    out[ch * (BATCH * NVARS) + row * 16 + l] = c_l;   // lane l owns c[l]

    __syncthreads();
    const int t2 = threadIdx.x;
    if (t2 < 60) {
        int it = t2 % 15, r2 = t2 / 15, gb = r2 * 3;
        out[OUT_PST + it * BATCH + blockIdx.x * 4 + r2] =
            res_st[it][gb] + res_st[it][gb + 1] + res_st[it][gb + 2];
    } else if (t2 < 120) {
        int t3 = t2 - 60;
        int it = t3 % 15, r2 = t3 / 15, gb = r2 * 3;
        out[OUT_FST + it * BATCH + blockIdx.x * 4 + r2] =
            fix_st[it][gb] + fix_st[it][gb + 1] + fix_st[it][gb + 2];
    } else if (t2 < 124) {
        int r2 = t2 - 120, gb = r2 * 3;
        float s = 0.f;
        for (int it = 0; it < ITERS; ++it)
            s += fix_st[it][gb] + fix_st[it][gb + 1] + fix_st[it][gb + 2];
        out[OUT_ACCF + blockIdx.x * 4 + r2] = s * (1.f / 15.f);
    } else if (t2 < 128) {
        int r2 = t2 - 124, gb = r2 * 3;
        float s = 0.f;
        for (int it = 0; it < ITERS; ++it)
            s += res_st[it][gb] + res_st[it][gb + 1] + res_st[it][gb + 2];
        out[OUT_ACCP + blockIdx.x * 4 + r2] = s * (1.f / 15.f);
    }
}

extern "C" void kernel_launch(void* const* d_in, const int* in_sizes, int n_in,
                              void* d_out, int out_size, void* d_ws, size_t ws_size,
                              hipStream_t stream)
{
    const float* P    = (const float*)d_in[0];
    const float* Pdm  = (const float*)d_in[1];
    const float* Pddm = (const float*)d_in[2];
    const float* lamv = (const float*)d_in[3];
    const float* lamp = (const float*)d_in[4];
    const float* lamr = (const float*)d_in[5];
    const float* cinv = (const float*)d_in[6];
    const float* cinp = (const float*)d_in[7];
    const float* cinr = (const float*)d_in[8];
    const float* beqv = (const float*)d_in[9];
    const float* beqp = (const float*)d_in[10];
    const float* beqr = (const float*)d_in[11];
    const float* c0v  = (const float*)d_in[12];
    const float* c0p  = (const float*)d_in[13];
    const float* c0r  = (const float*)d_in[14];
    float* ws = (float*)d_ws;

    prep_kernel<<<1, 648, 0, stream>>>(P, Pdm, Pddm, ws);
    solve_kernel<<<2048, 192, 0, stream>>>(P, Pdm, Pddm,
        lamv, lamp, lamr, cinv, cinp, cinr,
        beqv, beqp, beqr, c0v, c0p, c0r,
        (float*)d_out, ws);
}

// Round 18
// 194.572 us; speedup vs baseline: 3.3239x; 3.3239x over previous
//
#include <hip/hip_runtime.h>

#define NUMS   128
#define NVARS  16
#define BATCH  8192
#define ITERS  15

#define OUT_ACCF (3*BATCH*NVARS)
#define OUT_ACCP (OUT_ACCF + BATCH)
#define OUT_PST  (OUT_ACCP + BATCH)
#define OUT_FST  (OUT_PST + ITERS*BATCH)

typedef _Float16 f16;
typedef f16  f16x8 __attribute__((ext_vector_type(8)));
typedef float f32x4 __attribute__((ext_vector_type(4)));

// ---------------------------------------------------------------------------
// prep (unchanged R11): ws [0,324) = M (18x18) f32; [324,596) = Q padded [16][17]
// ---------------------------------------------------------------------------
__global__ void prep_kernel(const float* __restrict__ P, const float* __restrict__ Pd,
                            const float* __restrict__ Pdd, float* __restrict__ ws)
{
    __shared__ double GA[18][36];
    __shared__ float  ata[16][16];
    __shared__ double piv_s;
    const int t = threadIdx.x;

    if (t < 256) {
        int j = t >> 4, k = t & 15;
        float s = 0.f;
        for (int i = 0; i < NUMS; ++i)
            s += P[i*16+j]*P[i*16+k] + Pd[i*16+j]*Pd[i*16+k] + Pdd[i*16+j]*Pdd[i*16+k];
        ata[j][k] = 2.f * s;
    }
    __syncthreads();

    const int gi = t / 36, gj = t % 36;
    {
        double v;
        if (gj < 18) {
            if (gi < 16 && gj < 16)      v = (gi == gj ? 1.0 : 0.0) + (double)ata[gi][gj];
            else if (gi < 16)            v = (gj == 16) ? (double)P[gi] : (double)Pd[gi];
            else if (gj < 16)            v = (gi == 16) ? (double)P[gj] : (double)Pd[gj];
            else                         v = 0.0;
        } else {
            v = ((gj - 18) == gi) ? 1.0 : 0.0;
        }
        GA[gi][gj] = v;
    }
    __syncthreads();

    for (int k = 0; k < 18; ++k) {
        if (t == 0) piv_s = GA[k][k];
        __syncthreads();
        if (gi == k) GA[gi][gj] /= piv_s;
        __syncthreads();
        double f  = GA[gi][k];
        double rk = GA[k][gj];
        __syncthreads();
        if (gi != k) GA[gi][gj] -= f * rk;
        __syncthreads();
    }

    if (gj >= 18) ws[gi*18 + (gj - 18)] = (float)GA[gi][gj];
    if (t < 256)  ws[324 + (t >> 4)*17 + (t & 15)] = ata[t >> 4][t & 15];
    if (t >= 256 && t < 272) ws[324 + (t - 256)*17 + 16] = 0.f;
}

__device__ __forceinline__ unsigned pkh(float a, float b) {
    auto h = __builtin_amdgcn_cvt_pkrtz(a, b);   // __fp16 ext_vector(2)
    unsigned u; __builtin_memcpy(&u, &h, 4); return u;
}
__device__ __forceinline__ void uph(unsigned u, float& a, float& b) {
    __fp16 h[2]; __builtin_memcpy(&h, &u, 4);
    a = (float)h[0]; b = (float)h[1];
}
__device__ __forceinline__ f16x8 frg(uint4 u) {
    f16x8 r; __builtin_memcpy(&r, &u, 16); return r;
}
__device__ __forceinline__ f32x4 mfma16(f16x8 a, f16x8 b, f32x4 c) {
    return __builtin_amdgcn_mfma_f32_16x16x32_f16(a, b, c, 0, 0, 0);
}

// ---------------------------------------------------------------------------
// MFMA solver. Block = 192 thr = 3 waves; wave = 1 channel x 16 batch rows.
// Grid = 512.  All matvecs via mfma_f32_16x16x32_f16 (verified C/D map:
// col=lane&15, row=4*(lane>>4)+reg). k-maps of A/B operands only need mutual
// consistency (contraction is order-invariant).  A-fragments prestaged in LDS
// (channel-shared); uo packed f16 in regs; KKT rhs scaled 1/16 for f16 range.
// ---------------------------------------------------------------------------
__launch_bounds__(192, 1)
__global__ void solve_kernel(
    const float* __restrict__ P,    const float* __restrict__ Pd,   const float* __restrict__ Pdd,
    const float* __restrict__ lamv, const float* __restrict__ lamp, const float* __restrict__ lamr,
    const float* __restrict__ cinv, const float* __restrict__ cinp, const float* __restrict__ cinr,
    const float* __restrict__ beqv, const float* __restrict__ beqp, const float* __restrict__ beqr,
    const float* __restrict__ c0v,  const float* __restrict__ c0p,  const float* __restrict__ c0r,
    float* __restrict__ out, const float* __restrict__ ws)
{
    __shared__ __align__(16) uint4 Af1[24*64];   // GEMM1 A-frags (u = A c), 24KB
    __shared__ __align__(16) uint4 Af2[12*64];   // GEMM2 A-frags (pj = A^T h), 12KB
    __shared__ float res_st[ITERS][3][16];
    __shared__ float fix_st[ITERS][3][16];

    const int tid = threadIdx.x;

    // ---- stage A-fragments (once per block, channel-independent) ----
    for (int idx = tid; idx < 24*64; idx += 192) {
        int t = idx >> 6, l = idx & 63;
        int m = t >> 3;
        const float* src = (m == 0) ? P : (m == 1) ? Pd : Pdd;
        int cc = ((t & 7) << 4) + (l & 15);     // constraint row within m
        int gg = l >> 4;
        f16 v[8];
#pragma unroll
        for (int e = 0; e < 8; ++e) {
            int k = 8*gg + e;                   // var index (zero-pad k>=16)
            v[e] = (k < 16) ? (f16)src[cc*16 + k] : (f16)0.f;
        }
        uint4 u; __builtin_memcpy(&u, v, 16);
        Af1[idx] = u;
    }
    for (int idx = tid; idx < 12*64; idx += 192) {
        int q = idx >> 6, l = idx & 63;
        int m = q >> 2;
        const float* src = (m == 0) ? P : (m == 1) ? Pd : Pdd;
        int gg = l >> 4;
        f16 v[8];
#pragma unroll
        for (int e = 0; e < 8; ++e) {
            int cc = ((q & 3) << 5) + 8*gg + e; // constraint within m (K=32 chunk)
            v[e] = (f16)src[cc*16 + (l & 15)];
        }
        uint4 u; __builtin_memcpy(&u, v, 16);
        Af2[idx] = u;
    }

    const int l   = tid & 63;
    const int ch  = tid >> 6;      // wave = channel
    const int l15 = l & 15;        // batch-row within tile / fragment col
    const int g   = l >> 4;        // lane group
    const int row = blockIdx.x * 16 + l15;

    // M and Q fragments in registers (A-operands; row = var = l15)
    f16x8 Mf, Qf;
    {
        f16 mv[8], qv[8];
#pragma unroll
        for (int e = 0; e < 8; ++e) {
            int k = 8*g + e;
            float m_ = 0.f, q_ = 0.f;
            if (k < 16)      { m_ = ws[l15*18 + k]; q_ = ws[324 + l15*17 + k]; }
            else if (k < 18) { m_ = ws[l15*18 + k]; }   // Meq cols 16,17
            mv[e] = (f16)m_;
            qv[e] = (f16)q_;
        }
        __builtin_memcpy(&Mf, mv, 16);
        __builtin_memcpy(&Qf, qv, 16);
    }
    __syncthreads();

    const float* lam_p = (ch == 0) ? lamv : (ch == 1) ? lamp : lamr;
    const float* cin_p = (ch == 0) ? cinv : (ch == 1) ? cinp : cinr;
    const float* beq_p = (ch == 0) ? beqv : (ch == 1) ? beqp : beqr;
    const float* c0_p  = (ch == 0) ? c0v  : (ch == 1) ? c0p  : c0r;

    float bmx[3], bmn[3];
    bmx[0] = (ch == 0) ? 20.f : (ch == 1) ? 0.2f  : 0.25f;
    bmn[0] = (ch == 0) ? 12.f : (ch == 1) ? -0.2f : -0.25f;
    bmx[1] = (ch == 0) ? 3.f  : 0.25f;
    bmn[1] = (ch == 0) ? -3.f : -0.25f;
    bmx[2] = (ch == 0) ? 3.f  : 0.15f;
    bmn[2] = (ch == 0) ? -3.f : -0.15f;

    // ---- state: lane holds [row=l15][vars 4g..4g+3] (the D-map layout) ----
    f32x4 L4, c4, cq4, pj4;
    const float beq0 = beq_p[row*2], beq1 = beq_p[row*2 + 1];
    {
        float4 a = *(const float4*)(lam_p + row*16 + 4*g);
        float4 b = *(const float4*)(cin_p + row*16 + 4*g);
        L4 = (f32x4){a.x + b.x, a.y + b.y, a.z + b.z, a.w + b.w};
        float4 c0 = *(const float4*)(c0_p + row*16 + 4*g);
        c4 = (f32x4){c0.x, c0.y, c0.z, c0.w};
    }
    unsigned uo_pk[24][2];
    const f32x4 zero4 = {0.f, 0.f, 0.f, 0.f};
    const float S = 0.0625f;
    const int base = l15 + 16*(2*(g & 1));   // shfl base for redistributions
    const bool hi = (l >= 32);

    // B-frag builder from D-map 4 floats (k = var; groups 2,3 zero)
    auto buildB = [&](float s0, float s1, float s2, float s3) -> uint4 {
        unsigned p0 = pkh(s0, s1), p1 = pkh(s2, s3);
        unsigned w0 = (unsigned)__shfl((int)p0, base, 64);
        unsigned w1 = (unsigned)__shfl((int)p1, base, 64);
        unsigned w2 = (unsigned)__shfl((int)p0, base + 16, 64);
        unsigned w3 = (unsigned)__shfl((int)p1, base + 16, 64);
        uint4 r;
        r.x = (g < 2) ? w0 : 0u; r.y = (g < 2) ? w1 : 0u;
        r.z = (g < 2) ? w2 : 0u; r.w = (g < 2) ? w3 : 0u;
        return r;
    };

#define CLIP0(u_, h_) { \
    float x_ = (u_) - bmxm, rvp_ = fmaxf(x_, 0.f); \
    float y_ = (u_) - bmnm, rvm_ = fmaxf(-y_, 0.f); \
    (h_) = rvp_ - rvm_; }

#define CLIPN(u_, uo_, h_) { \
    float x_ = (u_) - bmxm, rvp_ = fmaxf(x_, 0.f), spn_ = rvp_ - x_; \
    float y_ = (u_) - bmnm, smn_ = fmaxf(y_, 0.f), rvm_ = smn_ - y_; \
    res2 += rvp_*rvp_ + rvm_*rvm_; (h_) = rvp_ - rvm_; \
    float xo_ = (uo_) - bmxm, spo_ = fmaxf(-xo_, 0.f); \
    float yo_ = (uo_) - bmnm, smo_ = fmaxf(yo_, 0.f); \
    float e1_ = spn_ - spo_, e2_ = smn_ - smo_; \
    ds2 += e1_*e1_ + e2_*e2_; }

#define BUILD_BH(bh_, ha0_, ha1_, hb0_, hb1_) { \
    unsigned a0 = (unsigned)__shfl((int)(ha0_), base, 64); \
    unsigned b0 = (unsigned)__shfl((int)(hb0_), base, 64); \
    unsigned a1 = (unsigned)__shfl((int)(ha1_), base, 64); \
    unsigned b1 = (unsigned)__shfl((int)(hb1_), base, 64); \
    unsigned a2 = (unsigned)__shfl((int)(ha0_), base + 16, 64); \
    unsigned b2 = (unsigned)__shfl((int)(hb0_), base + 16, 64); \
    unsigned a3 = (unsigned)__shfl((int)(ha1_), base + 16, 64); \
    unsigned b3 = (unsigned)__shfl((int)(hb1_), base + 16, 64); \
    bh_.x = hi ? b0 : a0; bh_.y = hi ? b1 : a1; \
    bh_.z = hi ? b2 : a2; bh_.w = hi ? b3 : a3; }

    // ---- init pass: cq0, uo0, pj0 from c0 ----
    {
        uint4 bc = buildB(c4[0], c4[1], c4[2], c4[3]);
        f16x8 bcf = frg(bc);
        cq4 = mfma16(Qf, bcf, zero4);
        f32x4 pja = zero4;
#pragma unroll
        for (int q = 0; q < 12; ++q) {
            const float bmxm = bmx[q >> 2], bmnm = bmn[q >> 2];
            f32x4 ua = mfma16(frg(Af1[(2*q)*64 + l]), bcf, zero4);
            f32x4 ub = mfma16(frg(Af1[(2*q+1)*64 + l]), bcf, zero4);
            float h0, h1, h2, h3;
            CLIP0(ua[0], h0) CLIP0(ua[1], h1) CLIP0(ua[2], h2) CLIP0(ua[3], h3)
            unsigned ha0 = pkh(h0, h1), ha1 = pkh(h2, h3);
            uo_pk[2*q][0] = pkh(ua[0], ua[1]); uo_pk[2*q][1] = pkh(ua[2], ua[3]);
            CLIP0(ub[0], h0) CLIP0(ub[1], h1) CLIP0(ub[2], h2) CLIP0(ub[3], h3)
            unsigned hb0 = pkh(h0, h1), hb1 = pkh(h2, h3);
            uo_pk[2*q+1][0] = pkh(ub[0], ub[1]); uo_pk[2*q+1][1] = pkh(ub[2], ub[3]);
            uint4 bh; BUILD_BH(bh, ha0, ha1, hb0, hb1)
            pja = mfma16(frg(Af2[q*64 + l]), frg(bh), pja);
        }
        pj4 = pja;
    }

    // ---- 15 ADMM iterations ----
    for (int it = 0; it < ITERS; ++it) {
        // KKT: c_new = M(L + cq - pj) + Meq beq   (rhs scaled 1/16 for f16)
        f32x4 r4 = L4 + cq4 - pj4;
        uint4 br = buildB(r4[0]*S, r4[1]*S, r4[2]*S, r4[3]*S);
        if (g == 2) br.x = pkh(beq0*S, beq1*S);
        f32x4 cn = mfma16(Mf, frg(br), zero4);
        cn = cn * 16.f;
        f32x4 cd = cn - c4;
        float cdel2 = cd[0]*cd[0] + cd[1]*cd[1] + cd[2]*cd[2] + cd[3]*cd[3];
        c4 = cn;

        uint4 bc = buildB(c4[0], c4[1], c4[2], c4[3]);
        f16x8 bcf = frg(bc);
        cq4 = mfma16(Qf, bcf, zero4);

        float res2 = 0.f, ds2 = 0.f;
        f32x4 pja = zero4;
#pragma unroll
        for (int q = 0; q < 12; ++q) {
            const float bmxm = bmx[q >> 2], bmnm = bmn[q >> 2];
            f32x4 ua = mfma16(frg(Af1[(2*q)*64 + l]), bcf, zero4);
            f32x4 ub = mfma16(frg(Af1[(2*q+1)*64 + l]), bcf, zero4);
            float uo0, uo1, uo2, uo3, h0, h1, h2, h3;
            uph(uo_pk[2*q][0], uo0, uo1); uph(uo_pk[2*q][1], uo2, uo3);
            CLIPN(ua[0], uo0, h0) CLIPN(ua[1], uo1, h1)
            CLIPN(ua[2], uo2, h2) CLIPN(ua[3], uo3, h3)
            unsigned ha0 = pkh(h0, h1), ha1 = pkh(h2, h3);
            uo_pk[2*q][0] = pkh(ua[0], ua[1]); uo_pk[2*q][1] = pkh(ua[2], ua[3]);
            uph(uo_pk[2*q+1][0], uo0, uo1); uph(uo_pk[2*q+1][1], uo2, uo3);
            CLIPN(ub[0], uo0, h0) CLIPN(ub[1], uo1, h1)
            CLIPN(ub[2], uo2, h2) CLIPN(ub[3], uo3, h3)
            unsigned hb0 = pkh(h0, h1), hb1 = pkh(h2, h3);
            uo_pk[2*q+1][0] = pkh(ub[0], ub[1]); uo_pk[2*q+1][1] = pkh(ub[2], ub[3]);
            uint4 bh; BUILD_BH(bh, ha0, ha1, hb0, hb1)
            pja = mfma16(frg(Af2[q*64 + l]), frg(bh), pja);
        }
        pj4 = pja;
        float pj2 = pj4[0]*pj4[0] + pj4[1]*pj4[1] + pj4[2]*pj4[2] + pj4[3]*pj4[3];
        L4 = L4 - pj4;

        // all-reduce the 4 scalars over the 4 lane-groups (same batch row)
        res2  += __shfl_xor(res2, 16, 64);  res2  += __shfl_xor(res2, 32, 64);
        ds2   += __shfl_xor(ds2, 16, 64);   ds2   += __shfl_xor(ds2, 32, 64);
        cdel2 += __shfl_xor(cdel2, 16, 64); cdel2 += __shfl_xor(cdel2, 32, 64);
        pj2   += __shfl_xor(pj2, 16, 64);   pj2   += __shfl_xor(pj2, 32, 64);

        if (g == 0) {
            res_st[it][ch][l15] = sqrtf(res2);
            fix_st[it][ch][l15] = sqrtf(pj2) + sqrtf(ds2) + sqrtf(cdel2);
        }
    }

    // ---- outputs ----
    {
        float4 o; o.x = c4[0]; o.y = c4[1]; o.z = c4[2]; o.w = c4[3];
        *(float4*)(out + ch*(BATCH*NVARS) + row*16 + 4*g) = o;
    }
    __syncthreads();
    for (int f = tid; f < 240; f += 192) {
        int it = f / 16, r = f % 16;
        out[OUT_PST + it*BATCH + blockIdx.x*16 + r] =
            res_st[it][0][r] + res_st[it][1][r] + res_st[it][2][r];
        out[OUT_FST + it*BATCH + blockIdx.x*16 + r] =
            fix_st[it][0][r] + fix_st[it][1][r] + fix_st[it][2][r];
    }
    if (tid < 16) {
        float s = 0.f;
        for (int it = 0; it < ITERS; ++it)
            s += res_st[it][0][tid] + res_st[it][1][tid] + res_st[it][2][tid];
        out[OUT_ACCP + blockIdx.x*16 + tid] = s * (1.f / 15.f);
    } else if (tid < 32) {
        int r = tid - 16;
        float s = 0.f;
        for (int it = 0; it < ITERS; ++it)
            s += fix_st[it][0][r] + fix_st[it][1][r] + fix_st[it][2][r];
        out[OUT_ACCF + blockIdx.x*16 + r] = s * (1.f / 15.f);
    }
}

extern "C" void kernel_launch(void* const* d_in, const int* in_sizes, int n_in,
                              void* d_out, int out_size, void* d_ws, size_t ws_size,
                              hipStream_t stream)
{
    const float* P    = (const float*)d_in[0];
    const float* Pdm  = (const float*)d_in[1];
    const float* Pddm = (const float*)d_in[2];
    const float* lamv = (const float*)d_in[3];
    const float* lamp = (const float*)d_in[4];
    const float* lamr = (const float*)d_in[5];
    const float* cinv = (const float*)d_in[6];
    const float* cinp = (const float*)d_in[7];
    const float* cinr = (const float*)d_in[8];
    const float* beqv = (const float*)d_in[9];
    const float* beqp = (const float*)d_in[10];
    const float* beqr = (const float*)d_in[11];
    const float* c0v  = (const float*)d_in[12];
    const float* c0p  = (const float*)d_in[13];
    const float* c0r  = (const float*)d_in[14];
    float* ws = (float*)d_ws;

    prep_kernel<<<1, 648, 0, stream>>>(P, Pdm, Pddm, ws);
    solve_kernel<<<512, 192, 0, stream>>>(P, Pdm, Pddm,
        lamv, lamp, lamr, cinv, cinp, cinr,
        beqv, beqp, beqr, c0v, c0p, c0r,
        (float*)d_out, ws);
}

// Round 19
// 151.205 us; speedup vs baseline: 4.2772x; 1.2868x over previous
//
#include <hip/hip_runtime.h>

#define NUMS   128
#define NVARS  16
#define BATCH  8192
#define ITERS  15

#define OUT_ACCF (3*BATCH*NVARS)
#define OUT_ACCP (OUT_ACCF + BATCH)
#define OUT_PST  (OUT_ACCP + BATCH)
#define OUT_FST  (OUT_PST + ITERS*BATCH)

typedef _Float16 f16;
typedef f16  f16x8 __attribute__((ext_vector_type(8)));
typedef float f32x4 __attribute__((ext_vector_type(4)));
typedef __fp16 hv2 __attribute__((ext_vector_type(2)));

// ---------------------------------------------------------------------------
// prep (unchanged): ws [0,324) = M (18x18) f32; [324,596) = Q padded [16][17]
// ---------------------------------------------------------------------------
__global__ void prep_kernel(const float* __restrict__ P, const float* __restrict__ Pd,
                            const float* __restrict__ Pdd, float* __restrict__ ws)
{
    __shared__ double GA[18][36];
    __shared__ float  ata[16][16];
    __shared__ double piv_s;
    const int t = threadIdx.x;

    if (t < 256) {
        int j = t >> 4, k = t & 15;
        float s = 0.f;
        for (int i = 0; i < NUMS; ++i)
            s += P[i*16+j]*P[i*16+k] + Pd[i*16+j]*Pd[i*16+k] + Pdd[i*16+j]*Pdd[i*16+k];
        ata[j][k] = 2.f * s;
    }
    __syncthreads();

    const int gi = t / 36, gj = t % 36;
    {
        double v;
        if (gj < 18) {
            if (gi < 16 && gj < 16)      v = (gi == gj ? 1.0 : 0.0) + (double)ata[gi][gj];
            else if (gi < 16)            v = (gj == 16) ? (double)P[gi] : (double)Pd[gi];
            else if (gj < 16)            v = (gi == 16) ? (double)P[gj] : (double)Pd[gj];
            else                         v = 0.0;
        } else {
            v = ((gj - 18) == gi) ? 1.0 : 0.0;
        }
        GA[gi][gj] = v;
    }
    __syncthreads();

    for (int k = 0; k < 18; ++k) {
        if (t == 0) piv_s = GA[k][k];
        __syncthreads();
        if (gi == k) GA[gi][gj] /= piv_s;
        __syncthreads();
        double f  = GA[gi][k];
        double rk = GA[k][gj];
        __syncthreads();
        if (gi != k) GA[gi][gj] -= f * rk;
        __syncthreads();
    }

    if (gj >= 18) ws[gi*18 + (gj - 18)] = (float)GA[gi][gj];
    if (t < 256)  ws[324 + (t >> 4)*17 + (t & 15)] = ata[t >> 4][t & 15];
    if (t >= 256 && t < 272) ws[324 + (t - 256)*17 + 16] = 0.f;
}

__device__ __forceinline__ hv2 pkh2(float a, float b) {
    return __builtin_amdgcn_cvt_pkrtz(a, b);
}
__device__ __forceinline__ unsigned h2u(hv2 h) {
    unsigned u; __builtin_memcpy(&u, &h, 4); return u;
}
__device__ __forceinline__ unsigned pkh(float a, float b) {
    return h2u(pkh2(a, b));
}
__device__ __forceinline__ f16x8 frg(uint4 u) {
    f16x8 r; __builtin_memcpy(&r, &u, 16); return r;
}
__device__ __forceinline__ f32x4 mfma16(f16x8 a, f16x8 b, f32x4 c) {
    return __builtin_amdgcn_mfma_f32_16x16x32_f16(a, b, c, 0, 0, 0);
}

// ---------------------------------------------------------------------------
// MFMA solver (R18 structure, 194us) + PACKED-F16 clip pipeline.
// R18 was VALU-bound (VALUBusy 50%, MfmaUtil 3.2%): ~1450 of ~1630 VALU/iter
// was the scalar f32 CLIPN chain. Clips now run on v_pk_* f16 vectors (2
// clips/instr): cvt_pkrtz packs ua/ub once (needed for uo anyway), clip math
// stays packed, h emerges packed for BUILD_BH, uo never unpacks. res2/ds2
// accumulate per-q in f16x2 (<=8 terms, no overflow) then fold to f32.
// ---------------------------------------------------------------------------
__launch_bounds__(192, 1)
__global__ void solve_kernel(
    const float* __restrict__ P,    const float* __restrict__ Pd,   const float* __restrict__ Pdd,
    const float* __restrict__ lamv, const float* __restrict__ lamp, const float* __restrict__ lamr,
    const float* __restrict__ cinv, const float* __restrict__ cinp, const float* __restrict__ cinr,
    const float* __restrict__ beqv, const float* __restrict__ beqp, const float* __restrict__ beqr,
    const float* __restrict__ c0v,  const float* __restrict__ c0p,  const float* __restrict__ c0r,
    float* __restrict__ out, const float* __restrict__ ws)
{
    __shared__ __align__(16) uint4 Af1[24*64];   // GEMM1 A-frags (u = A c), 24KB
    __shared__ __align__(16) uint4 Af2[12*64];   // GEMM2 A-frags (pj = A^T h), 12KB
    __shared__ float res_st[ITERS][3][16];
    __shared__ float fix_st[ITERS][3][16];

    const int tid = threadIdx.x;

    // ---- stage A-fragments (once per block, channel-independent) ----
    for (int idx = tid; idx < 24*64; idx += 192) {
        int t = idx >> 6, l = idx & 63;
        int m = t >> 3;
        const float* src = (m == 0) ? P : (m == 1) ? Pd : Pdd;
        int cc = ((t & 7) << 4) + (l & 15);
        int gg = l >> 4;
        f16 v[8];
#pragma unroll
        for (int e = 0; e < 8; ++e) {
            int k = 8*gg + e;
            v[e] = (k < 16) ? (f16)src[cc*16 + k] : (f16)0.f;
        }
        uint4 u; __builtin_memcpy(&u, v, 16);
        Af1[idx] = u;
    }
    for (int idx = tid; idx < 12*64; idx += 192) {
        int q = idx >> 6, l = idx & 63;
        int m = q >> 2;
        const float* src = (m == 0) ? P : (m == 1) ? Pd : Pdd;
        int gg = l >> 4;
        f16 v[8];
#pragma unroll
        for (int e = 0; e < 8; ++e) {
            int cc = ((q & 3) << 5) + 8*gg + e;
            v[e] = (f16)src[cc*16 + (l & 15)];
        }
        uint4 u; __builtin_memcpy(&u, v, 16);
        Af2[idx] = u;
    }

    const int l   = tid & 63;
    const int ch  = tid >> 6;
    const int l15 = l & 15;
    const int g   = l >> 4;
    const int row = blockIdx.x * 16 + l15;

    // M and Q fragments (A-operands; row = var = l15)
    f16x8 Mf, Qf;
    {
        f16 mv[8], qv[8];
#pragma unroll
        for (int e = 0; e < 8; ++e) {
            int k = 8*g + e;
            float m_ = 0.f, q_ = 0.f;
            if (k < 16)      { m_ = ws[l15*18 + k]; q_ = ws[324 + l15*17 + k]; }
            else if (k < 18) { m_ = ws[l15*18 + k]; }
            mv[e] = (f16)m_;
            qv[e] = (f16)q_;
        }
        __builtin_memcpy(&Mf, mv, 16);
        __builtin_memcpy(&Qf, qv, 16);
    }
    __syncthreads();

    const float* lam_p = (ch == 0) ? lamv : (ch == 1) ? lamp : lamr;
    const float* cin_p = (ch == 0) ? cinv : (ch == 1) ? cinp : cinr;
    const float* beq_p = (ch == 0) ? beqv : (ch == 1) ? beqp : beqr;
    const float* c0_p  = (ch == 0) ? c0v  : (ch == 1) ? c0p  : c0r;

    float bmx[3], bmn[3];
    bmx[0] = (ch == 0) ? 20.f : (ch == 1) ? 0.2f  : 0.25f;
    bmn[0] = (ch == 0) ? 12.f : (ch == 1) ? -0.2f : -0.25f;
    bmx[1] = (ch == 0) ? 3.f  : 0.25f;
    bmn[1] = (ch == 0) ? -3.f : -0.25f;
    bmx[2] = (ch == 0) ? 3.f  : 0.15f;
    bmn[2] = (ch == 0) ? -3.f : -0.15f;

    // packed bounds per m
    hv2 bmax2h[3], bmin2h[3];
#pragma unroll
    for (int m = 0; m < 3; ++m) {
        bmax2h[m] = pkh2(bmx[m], bmx[m]);
        bmin2h[m] = pkh2(bmn[m], bmn[m]);
    }
    const hv2 z2 = pkh2(0.f, 0.f);

    // ---- state: lane holds [row=l15][vars 4g..4g+3] ----
    f32x4 L4, c4, cq4, pj4;
    const float beq0 = beq_p[row*2], beq1 = beq_p[row*2 + 1];
    {
        float4 a = *(const float4*)(lam_p + row*16 + 4*g);
        float4 b = *(const float4*)(cin_p + row*16 + 4*g);
        L4 = (f32x4){a.x + b.x, a.y + b.y, a.z + b.z, a.w + b.w};
        float4 c0 = *(const float4*)(c0_p + row*16 + 4*g);
        c4 = (f32x4){c0.x, c0.y, c0.z, c0.w};
    }
    hv2 uo2[24][2];                       // packed u_old (2 rows per entry)
    const f32x4 zero4 = {0.f, 0.f, 0.f, 0.f};
    const float S = 0.0625f;
    const int base = l15 + 16*(2*(g & 1));
    const bool hi = (l >= 32);

    auto buildB = [&](float s0, float s1, float s2, float s3) -> uint4 {
        unsigned p0 = pkh(s0, s1), p1 = pkh(s2, s3);
        unsigned w0 = (unsigned)__shfl((int)p0, base, 64);
        unsigned w1 = (unsigned)__shfl((int)p1, base, 64);
        unsigned w2 = (unsigned)__shfl((int)p0, base + 16, 64);
        unsigned w3 = (unsigned)__shfl((int)p1, base + 16, 64);
        uint4 r;
        r.x = (g < 2) ? w0 : 0u; r.y = (g < 2) ? w1 : 0u;
        r.z = (g < 2) ? w2 : 0u; r.w = (g < 2) ? w3 : 0u;
        return r;
    };

// packed clip, init version (no res/ds)
#define CLIPP0(u2_, h2_) { \
    hv2 x2_ = (u2_) - bmax2, rvp2_ = __builtin_elementwise_max(x2_, z2); \
    hv2 y2_ = (u2_) - bmin2, rvm2_ = __builtin_elementwise_max(-y2_, z2); \
    (h2_) = rvp2_ - rvm2_; }

// packed clip, full version: accumulates ra2/da2 (f16x2), reads uo2_ old
#define CLIPP(u2_, uo2_, h2_) { \
    hv2 x2_ = (u2_) - bmax2, rvp2_ = __builtin_elementwise_max(x2_, z2); \
    hv2 spn2_ = rvp2_ - x2_; \
    hv2 y2_ = (u2_) - bmin2, smn2_ = __builtin_elementwise_max(y2_, z2); \
    hv2 rvm2_ = smn2_ - y2_; \
    ra2 += rvp2_*rvp2_ + rvm2_*rvm2_; \
    (h2_) = rvp2_ - rvm2_; \
    hv2 xo2_ = (uo2_) - bmax2, spo2_ = __builtin_elementwise_max(-xo2_, z2); \
    hv2 yo2_ = (uo2_) - bmin2, smo2_ = __builtin_elementwise_max(yo2_, z2); \
    hv2 e1_ = spn2_ - spo2_, e2_ = smn2_ - smo2_; \
    da2 += e1_*e1_ + e2_*e2_; }

#define BUILD_BH(bh_, ha0_, ha1_, hb0_, hb1_) { \
    unsigned a0 = (unsigned)__shfl((int)(ha0_), base, 64); \
    unsigned b0 = (unsigned)__shfl((int)(hb0_), base, 64); \
    unsigned a1 = (unsigned)__shfl((int)(ha1_), base, 64); \
    unsigned b1 = (unsigned)__shfl((int)(hb1_), base, 64); \
    unsigned a2 = (unsigned)__shfl((int)(ha0_), base + 16, 64); \
    unsigned b2 = (unsigned)__shfl((int)(hb0_), base + 16, 64); \
    unsigned a3 = (unsigned)__shfl((int)(ha1_), base + 16, 64); \
    unsigned b3 = (unsigned)__shfl((int)(hb1_), base + 16, 64); \
    bh_.x = hi ? b0 : a0; bh_.y = hi ? b1 : a1; \
    bh_.z = hi ? b2 : a2; bh_.w = hi ? b3 : a3; }

    // ---- init pass: cq0, uo0, pj0 from c0 ----
    {
        uint4 bc = buildB(c4[0], c4[1], c4[2], c4[3]);
        f16x8 bcf = frg(bc);
        cq4 = mfma16(Qf, bcf, zero4);
        f32x4 pja = zero4;
#pragma unroll
        for (int q = 0; q < 12; ++q) {
            const hv2 bmax2 = bmax2h[q >> 2], bmin2 = bmin2h[q >> 2];
            f32x4 ua = mfma16(frg(Af1[(2*q)*64 + l]), bcf, zero4);
            f32x4 ub = mfma16(frg(Af1[(2*q+1)*64 + l]), bcf, zero4);
            hv2 ua01 = pkh2(ua[0], ua[1]), ua23 = pkh2(ua[2], ua[3]);
            hv2 ub01 = pkh2(ub[0], ub[1]), ub23 = pkh2(ub[2], ub[3]);
            hv2 h2a0, h2a1, h2b0, h2b1;
            CLIPP0(ua01, h2a0) CLIPP0(ua23, h2a1)
            CLIPP0(ub01, h2b0) CLIPP0(ub23, h2b1)
            uo2[2*q][0] = ua01; uo2[2*q][1] = ua23;
            uo2[2*q+1][0] = ub01; uo2[2*q+1][1] = ub23;
            unsigned ha0 = h2u(h2a0), ha1 = h2u(h2a1);
            unsigned hb0 = h2u(h2b0), hb1 = h2u(h2b1);
            uint4 bh; BUILD_BH(bh, ha0, ha1, hb0, hb1)
            pja = mfma16(frg(Af2[q*64 + l]), frg(bh), pja);
        }
        pj4 = pja;
    }

    // ---- 15 ADMM iterations ----
    for (int it = 0; it < ITERS; ++it) {
        // KKT: c_new = M(L + cq - pj) + Meq beq (rhs scaled 1/16 for f16)
        f32x4 r4 = L4 + cq4 - pj4;
        uint4 br = buildB(r4[0]*S, r4[1]*S, r4[2]*S, r4[3]*S);
        if (g == 2) br.x = pkh(beq0*S, beq1*S);
        f32x4 cn = mfma16(Mf, frg(br), zero4);
        cn = cn * 16.f;
        f32x4 cd = cn - c4;
        float cdel2 = cd[0]*cd[0] + cd[1]*cd[1] + cd[2]*cd[2] + cd[3]*cd[3];
        c4 = cn;

        uint4 bc = buildB(c4[0], c4[1], c4[2], c4[3]);
        f16x8 bcf = frg(bc);
        cq4 = mfma16(Qf, bcf, zero4);

        float res2 = 0.f, ds2 = 0.f;
        f32x4 pja = zero4;
#pragma unroll
        for (int q = 0; q < 12; ++q) {
            const hv2 bmax2 = bmax2h[q >> 2], bmin2 = bmin2h[q >> 2];
            f32x4 ua = mfma16(frg(Af1[(2*q)*64 + l]), bcf, zero4);
            f32x4 ub = mfma16(frg(Af1[(2*q+1)*64 + l]), bcf, zero4);
            hv2 ua01 = pkh2(ua[0], ua[1]), ua23 = pkh2(ua[2], ua[3]);
            hv2 ub01 = pkh2(ub[0], ub[1]), ub23 = pkh2(ub[2], ub[3]);
            hv2 ra2 = z2, da2 = z2;
            hv2 h2a0, h2a1, h2b0, h2b1;
            CLIPP(ua01, uo2[2*q][0], h2a0) CLIPP(ua23, uo2[2*q][1], h2a1)
            CLIPP(ub01, uo2[2*q+1][0], h2b0) CLIPP(ub23, uo2[2*q+1][1], h2b1)
            uo2[2*q][0] = ua01; uo2[2*q][1] = ua23;
            uo2[2*q+1][0] = ub01; uo2[2*q+1][1] = ub23;
            res2 += (float)ra2[0] + (float)ra2[1];
            ds2  += (float)da2[0] + (float)da2[1];
            unsigned ha0 = h2u(h2a0), ha1 = h2u(h2a1);
            unsigned hb0 = h2u(h2b0), hb1 = h2u(h2b1);
            uint4 bh; BUILD_BH(bh, ha0, ha1, hb0, hb1)
            pja = mfma16(frg(Af2[q*64 + l]), frg(bh), pja);
        }
        pj4 = pja;
        float pj2 = pj4[0]*pj4[0] + pj4[1]*pj4[1] + pj4[2]*pj4[2] + pj4[3]*pj4[3];
        L4 = L4 - pj4;

        // all-reduce the 4 scalars over the 4 lane-groups (same batch row)
        res2  += __shfl_xor(res2, 16, 64);  res2  += __shfl_xor(res2, 32, 64);
        ds2   += __shfl_xor(ds2, 16, 64);   ds2   += __shfl_xor(ds2, 32, 64);
        cdel2 += __shfl_xor(cdel2, 16, 64); cdel2 += __shfl_xor(cdel2, 32, 64);
        pj2   += __shfl_xor(pj2, 16, 64);   pj2   += __shfl_xor(pj2, 32, 64);

        if (g == 0) {
            res_st[it][ch][l15] = sqrtf(res2);
            fix_st[it][ch][l15] = sqrtf(pj2) + sqrtf(ds2) + sqrtf(cdel2);
        }
    }

    // ---- outputs ----
    {
        float4 o; o.x = c4[0]; o.y = c4[1]; o.z = c4[2]; o.w = c4[3];
        *(float4*)(out + ch*(BATCH*NVARS) + row*16 + 4*g) = o;
    }
    __syncthreads();
    for (int f = tid; f < 240; f += 192) {
        int it = f / 16, r = f % 16;
        out[OUT_PST + it*BATCH + blockIdx.x*16 + r] =
            res_st[it][0][r] + res_st[it][1][r] + res_st[it][2][r];
        out[OUT_FST + it*BATCH + blockIdx.x*16 + r] =
            fix_st[it][0][r] + fix_st[it][1][r] + fix_st[it][2][r];
    }
    if (tid < 16) {
        float s = 0.f;
        for (int it = 0; it < ITERS; ++it)
            s += res_st[it][0][tid] + res_st[it][1][tid] + res_st[it][2][tid];
        out[OUT_ACCP + blockIdx.x*16 + tid] = s * (1.f / 15.f);
    } else if (tid < 32) {
        int r = tid - 16;
        float s = 0.f;
        for (int it = 0; it < ITERS; ++it)
            s += fix_st[it][0][r] + fix_st[it][1][r] + fix_st[it][2][r];
        out[OUT_ACCF + blockIdx.x*16 + r] = s * (1.f / 15.f);
    }
}

extern "C" void kernel_launch(void* const* d_in, const int* in_sizes, int n_in,
                              void* d_out, int out_size, void* d_ws, size_t ws_size,
                              hipStream_t stream)
{
    const float* P    = (const float*)d_in[0];
    const float* Pdm  = (const float*)d_in[1];
    const float* Pddm = (const float*)d_in[2];
    const float* lamv = (const float*)d_in[3];
    const float* lamp = (const float*)d_in[4];
    const float* lamr = (const float*)d_in[5];
    const float* cinv = (const float*)d_in[6];
    const float* cinp = (const float*)d_in[7];
    const float* cinr = (const float*)d_in[8];
    const float* beqv = (const float*)d_in[9];
    const float* beqp = (const float*)d_in[10];
    const float* beqr = (const float*)d_in[11];
    const float* c0v  = (const float*)d_in[12];
    const float* c0p  = (const float*)d_in[13];
    const float* c0r  = (const float*)d_in[14];
    float* ws = (float*)d_ws;

    prep_kernel<<<1, 648, 0, stream>>>(P, Pdm, Pddm, ws);
    solve_kernel<<<512, 192, 0, stream>>>(P, Pdm, Pddm,
        lamv, lamp, lamr, cinv, cinp, cinr,
        beqv, beqp, beqr, c0v, c0p, c0r,
        (float*)d_out, ws);
}

// Round 23
// 112.466 us; speedup vs baseline: 5.7505x; 1.3445x over previous
//
#include <hip/hip_runtime.h>

#define NUMS   128
#define NVARS  16
#define BATCH  8192
#define ITERS  15

#define OUT_ACCF (3*BATCH*NVARS)
#define OUT_ACCP (OUT_ACCF + BATCH)
#define OUT_PST  (OUT_ACCP + BATCH)
#define OUT_FST  (OUT_PST + ITERS*BATCH)

typedef _Float16 f16;
typedef f16  f16x8 __attribute__((ext_vector_type(8)));
typedef float f32x4 __attribute__((ext_vector_type(4)));
typedef __fp16 hv2 __attribute__((ext_vector_type(2)));

// ---------------------------------------------------------------------------
// prep (unchanged): ws [0,324) = M (18x18) f32; [324,596) = Q padded [16][17]
// ---------------------------------------------------------------------------
__global__ void prep_kernel(const float* __restrict__ P, const float* __restrict__ Pd,
                            const float* __restrict__ Pdd, float* __restrict__ ws)
{
    __shared__ double GA[18][36];
    __shared__ float  ata[16][16];
    __shared__ double piv_s;
    const int t = threadIdx.x;

    if (t < 256) {
        int j = t >> 4, k = t & 15;
        float s = 0.f;
        for (int i = 0; i < NUMS; ++i)
            s += P[i*16+j]*P[i*16+k] + Pd[i*16+j]*Pd[i*16+k] + Pdd[i*16+j]*Pdd[i*16+k];
        ata[j][k] = 2.f * s;
    }
    __syncthreads();

    const int gi = t / 36, gj = t % 36;
    {
        double v;
        if (gj < 18) {
            if (gi < 16 && gj < 16)      v = (gi == gj ? 1.0 : 0.0) + (double)ata[gi][gj];
            else if (gi < 16)            v = (gj == 16) ? (double)P[gi] : (double)Pd[gi];
            else if (gj < 16)            v = (gi == 16) ? (double)P[gj] : (double)Pd[gj];
            else                         v = 0.0;
        } else {
            v = ((gj - 18) == gi) ? 1.0 : 0.0;
        }
        GA[gi][gj] = v;
    }
    __syncthreads();

    for (int k = 0; k < 18; ++k) {
        if (t == 0) piv_s = GA[k][k];
        __syncthreads();
        if (gi == k) GA[gi][gj] /= piv_s;
        __syncthreads();
        double f  = GA[gi][k];
        double rk = GA[k][gj];
        __syncthreads();
        if (gi != k) GA[gi][gj] -= f * rk;
        __syncthreads();
    }

    if (gj >= 18) ws[gi*18 + (gj - 18)] = (float)GA[gi][gj];
    if (t < 256)  ws[324 + (t >> 4)*17 + (t & 15)] = ata[t >> 4][t & 15];
    if (t >= 256 && t < 272) ws[324 + (t - 256)*17 + 16] = 0.f;
}

__device__ __forceinline__ hv2 pkh2(float a, float b) {
    return __builtin_amdgcn_cvt_pkrtz(a, b);
}
__device__ __forceinline__ unsigned h2u(hv2 h) {
    unsigned u; __builtin_memcpy(&u, &h, 4); return u;
}
__device__ __forceinline__ unsigned pkh(float a, float b) {
    return h2u(pkh2(a, b));
}
__device__ __forceinline__ f16x8 frg(uint4 u) {
    f16x8 r; __builtin_memcpy(&r, &u, 16); return r;
}
__device__ __forceinline__ f32x4 mfma16(f16x8 a, f16x8 b, f32x4 c) {
    return __builtin_amdgcn_mfma_f32_16x16x32_f16(a, b, c, 0, 0, 0);
}

// ---------------------------------------------------------------------------
// MFMA solver, SHUFFLE-FREE k-map. R19 (151us) was latency-bound with ~108
// ds_bpermute/iter between MFMA stages (buildB + BUILD_BH). MFMA contraction
// only needs A,B to agree on the (lane-group,element)->k map, which we choose
// to MATCH the D-layout residency: slot (g,e<4) <-> var/row 4g+e, slot
// (g=0,e=4|5) <-> KKT eq-cols (beq is lane-local). B-fragments are then pure
// register packs: bc/br = 2x cvt_pkrtz; bh = bitcast of clip output. All data
// shuffles eliminated; only the 8 norm-butterfly shfl remain. pja split into
// 2 accumulators (6-deep MFMA chain). Arithmetic value-identical to R19.
// ---------------------------------------------------------------------------
__launch_bounds__(192, 1)
__global__ void solve_kernel(
    const float* __restrict__ P,    const float* __restrict__ Pd,   const float* __restrict__ Pdd,
    const float* __restrict__ lamv, const float* __restrict__ lamp, const float* __restrict__ lamr,
    const float* __restrict__ cinv, const float* __restrict__ cinp, const float* __restrict__ cinr,
    const float* __restrict__ beqv, const float* __restrict__ beqp, const float* __restrict__ beqr,
    const float* __restrict__ c0v,  const float* __restrict__ c0p,  const float* __restrict__ c0r,
    float* __restrict__ out, const float* __restrict__ ws)
{
    __shared__ __align__(16) uint4 Af1[24*64];   // GEMM1 A-frags (u = A c), 24KB
    __shared__ __align__(16) uint4 Af2[12*64];   // GEMM2 A-frags (pj = A^T h), 12KB
    __shared__ float res_st[ITERS][3][16];
    __shared__ float fix_st[ITERS][3][16];

    const int tid = threadIdx.x;

    // ---- stage A-fragments with the D-layout-matched k-map ----
    // Af1: lane (gg, mrow): e<4 -> A[cc, 4gg+e]; e>=4 -> 0.
    for (int idx = tid; idx < 24*64; idx += 192) {
        int t = idx >> 6, l = idx & 63;
        int m = t >> 3;
        const float* src = (m == 0) ? P : (m == 1) ? Pd : Pdd;
        int cc = ((t & 7) << 4) + (l & 15);
        int gg = l >> 4;
        f16 v[8];
#pragma unroll
        for (int e = 0; e < 8; ++e)
            v[e] = (e < 4) ? (f16)src[cc*16 + 4*gg + e] : (f16)0.f;
        uint4 u; __builtin_memcpy(&u, v, 16);
        Af1[idx] = u;
    }
    // Af2: lane (gg, var): e<4: rows 4gg+e of tile 2q; e>=4: rows 4gg+(e-4)
    // of tile 2q+1.  Value = A[cc, var].
    for (int idx = tid; idx < 12*64; idx += 192) {
        int q = idx >> 6, l = idx & 63;
        int m = q >> 2;
        const float* src = (m == 0) ? P : (m == 1) ? Pd : Pdd;
        int gg = l >> 4;
        int var = l & 15;
        f16 v[8];
#pragma unroll
        for (int e = 0; e < 8; ++e) {
            int tile = e >> 2;
            int cc = ((q & 3) << 5) + tile*16 + 4*gg + (e & 3);
            v[e] = (f16)src[cc*16 + var];
        }
        uint4 u; __builtin_memcpy(&u, v, 16);
        Af2[idx] = u;
    }

    const int l   = tid & 63;
    const int ch  = tid >> 6;
    const int l15 = l & 15;
    const int g   = l >> 4;
    const int row = blockIdx.x * 16 + l15;

    // M and Q fragments (same k-map): e<4 -> col 4g+e; g==0: e=4,5 -> cols 16,17
    f16x8 Mf, Qf;
    {
        f16 mv[8], qv[8];
#pragma unroll
        for (int e = 0; e < 8; ++e) { mv[e] = (f16)0.f; qv[e] = (f16)0.f; }
#pragma unroll
        for (int e = 0; e < 4; ++e) {
            int k = 4*g + e;
            mv[e] = (f16)ws[l15*18 + k];
            qv[e] = (f16)ws[324 + l15*17 + k];
        }
        if (g == 0) {
            mv[4] = (f16)ws[l15*18 + 16];
            mv[5] = (f16)ws[l15*18 + 17];
        }
        __builtin_memcpy(&Mf, mv, 16);
        __builtin_memcpy(&Qf, qv, 16);
    }
    __syncthreads();

    const float* lam_p = (ch == 0) ? lamv : (ch == 1) ? lamp : lamr;
    const float* cin_p = (ch == 0) ? cinv : (ch == 1) ? cinp : cinr;
    const float* beq_p = (ch == 0) ? beqv : (ch == 1) ? beqp : beqr;
    const float* c0_p  = (ch == 0) ? c0v  : (ch == 1) ? c0p  : c0r;

    float bmx[3], bmn[3];
    bmx[0] = (ch == 0) ? 20.f : (ch == 1) ? 0.2f  : 0.25f;
    bmn[0] = (ch == 0) ? 12.f : (ch == 1) ? -0.2f : -0.25f;
    bmx[1] = (ch == 0) ? 3.f  : 0.25f;
    bmn[1] = (ch == 0) ? -3.f : -0.25f;
    bmx[2] = (ch == 0) ? 3.f  : 0.15f;
    bmn[2] = (ch == 0) ? -3.f : -0.15f;

    hv2 bmax2h[3], bmin2h[3];
#pragma unroll
    for (int m = 0; m < 3; ++m) {
        bmax2h[m] = pkh2(bmx[m], bmx[m]);
        bmin2h[m] = pkh2(bmn[m], bmn[m]);
    }
    const hv2 z2 = pkh2(0.f, 0.f);

    // ---- state: lane (g,l15) holds [row=l15][vars 4g..4g+3] ----
    f32x4 L4, c4, cq4, pj4;
    const float beq0 = beq_p[row*2], beq1 = beq_p[row*2 + 1];
    {
        float4 a = *(const float4*)(lam_p + row*16 + 4*g);
        float4 b = *(const float4*)(cin_p + row*16 + 4*g);
        L4 = (f32x4){a.x + b.x, a.y + b.y, a.z + b.z, a.w + b.w};
        float4 c0 = *(const float4*)(c0_p + row*16 + 4*g);
        c4 = (f32x4){c0.x, c0.y, c0.z, c0.w};
    }
    hv2 uo2[24][2];
    const f32x4 zero4 = {0.f, 0.f, 0.f, 0.f};
    const float S = 0.0625f;

#define CLIPP0(u2_, h2_) { \
    hv2 x2_ = (u2_) - bmax2, rvp2_ = __builtin_elementwise_max(x2_, z2); \
    hv2 y2_ = (u2_) - bmin2, rvm2_ = __builtin_elementwise_max(-y2_, z2); \
    (h2_) = rvp2_ - rvm2_; }

#define CLIPP(u2_, uo2_, h2_) { \
    hv2 x2_ = (u2_) - bmax2, rvp2_ = __builtin_elementwise_max(x2_, z2); \
    hv2 spn2_ = rvp2_ - x2_; \
    hv2 y2_ = (u2_) - bmin2, smn2_ = __builtin_elementwise_max(y2_, z2); \
    hv2 rvm2_ = smn2_ - y2_; \
    ra2 += rvp2_*rvp2_ + rvm2_*rvm2_; \
    (h2_) = rvp2_ - rvm2_; \
    hv2 xo2_ = (uo2_) - bmax2, spo2_ = __builtin_elementwise_max(-xo2_, z2); \
    hv2 yo2_ = (uo2_) - bmin2, smo2_ = __builtin_elementwise_max(yo2_, z2); \
    hv2 e1_ = spn2_ - spo2_, e2_ = smn2_ - smo2_; \
    da2 += e1_*e1_ + e2_*e2_; }

    // ---- init pass: cq0, uo0, pj0 from c0 ----
    {
        uint4 bc; bc.x = pkh(c4[0], c4[1]); bc.y = pkh(c4[2], c4[3]); bc.z = 0u; bc.w = 0u;
        f16x8 bcf = frg(bc);
        cq4 = mfma16(Qf, bcf, zero4);
        f32x4 pja0 = zero4, pja1 = zero4;
#pragma unroll
        for (int q = 0; q < 12; ++q) {
            const hv2 bmax2 = bmax2h[q >> 2], bmin2 = bmin2h[q >> 2];
            f32x4 ua = mfma16(frg(Af1[(2*q)*64 + l]), bcf, zero4);
            f32x4 ub = mfma16(frg(Af1[(2*q+1)*64 + l]), bcf, zero4);
            hv2 ua01 = pkh2(ua[0], ua[1]), ua23 = pkh2(ua[2], ua[3]);
            hv2 ub01 = pkh2(ub[0], ub[1]), ub23 = pkh2(ub[2], ub[3]);
            hv2 h2a0, h2a1, h2b0, h2b1;
            CLIPP0(ua01, h2a0) CLIPP0(ua23, h2a1)
            CLIPP0(ub01, h2b0) CLIPP0(ub23, h2b1)
            uo2[2*q][0] = ua01; uo2[2*q][1] = ua23;
            uo2[2*q+1][0] = ub01; uo2[2*q+1][1] = ub23;
            uint4 bh;
            bh.x = h2u(h2a0); bh.y = h2u(h2a1); bh.z = h2u(h2b0); bh.w = h2u(h2b1);
            if (q & 1) pja1 = mfma16(frg(Af2[q*64 + l]), frg(bh), pja1);
            else       pja0 = mfma16(frg(Af2[q*64 + l]), frg(bh), pja0);
        }
        pj4 = pja0 + pja1;
    }

    // ---- 15 ADMM iterations ----
    for (int it = 0; it < ITERS; ++it) {
        // KKT: c_new = M(L + cq - pj) + Meq beq (rhs scaled 1/16 for f16)
        f32x4 r4 = L4 + cq4 - pj4;
        uint4 br;
        br.x = pkh(r4[0]*S, r4[1]*S);
        br.y = pkh(r4[2]*S, r4[3]*S);
        br.z = (g == 0) ? pkh(beq0*S, beq1*S) : 0u;
        br.w = 0u;
        f32x4 cn = mfma16(Mf, frg(br), zero4);
        cn = cn * 16.f;
        f32x4 cd = cn - c4;
        float cdel2 = cd[0]*cd[0] + cd[1]*cd[1] + cd[2]*cd[2] + cd[3]*cd[3];
        c4 = cn;

        uint4 bc; bc.x = pkh(c4[0], c4[1]); bc.y = pkh(c4[2], c4[3]); bc.z = 0u; bc.w = 0u;
        f16x8 bcf = frg(bc);
        cq4 = mfma16(Qf, bcf, zero4);

        float res2 = 0.f, ds2 = 0.f;
        f32x4 pja0 = zero4, pja1 = zero4;
#pragma unroll
        for (int q = 0; q < 12; ++q) {
            const hv2 bmax2 = bmax2h[q >> 2], bmin2 = bmin2h[q >> 2];
            f32x4 ua = mfma16(frg(Af1[(2*q)*64 + l]), bcf, zero4);
            f32x4 ub = mfma16(frg(Af1[(2*q+1)*64 + l]), bcf, zero4);
            hv2 ua01 = pkh2(ua[0], ua[1]), ua23 = pkh2(ua[2], ua[3]);
            hv2 ub01 = pkh2(ub[0], ub[1]), ub23 = pkh2(ub[2], ub[3]);
            hv2 ra2 = z2, da2 = z2;
            hv2 h2a0, h2a1, h2b0, h2b1;
            CLIPP(ua01, uo2[2*q][0], h2a0) CLIPP(ua23, uo2[2*q][1], h2a1)
            CLIPP(ub01, uo2[2*q+1][0], h2b0) CLIPP(ub23, uo2[2*q+1][1], h2b1)
            uo2[2*q][0] = ua01; uo2[2*q][1] = ua23;
            uo2[2*q+1][0] = ub01; uo2[2*q+1][1] = ub23;
            res2 += (float)ra2[0] + (float)ra2[1];
            ds2  += (float)da2[0] + (float)da2[1];
            uint4 bh;
            bh.x = h2u(h2a0); bh.y = h2u(h2a1); bh.z = h2u(h2b0); bh.w = h2u(h2b1);
            if (q & 1) pja1 = mfma16(frg(Af2[q*64 + l]), frg(bh), pja1);
            else       pja0 = mfma16(frg(Af2[q*64 + l]), frg(bh), pja0);
        }
        pj4 = pja0 + pja1;
        float pj2 = pj4[0]*pj4[0] + pj4[1]*pj4[1] + pj4[2]*pj4[2] + pj4[3]*pj4[3];
        L4 = L4 - pj4;

        // all-reduce the 4 scalars over the 4 lane-groups (same batch row)
        res2  += __shfl_xor(res2, 16, 64);  res2  += __shfl_xor(res2, 32, 64);
        ds2   += __shfl_xor(ds2, 16, 64);   ds2   += __shfl_xor(ds2, 32, 64);
        cdel2 += __shfl_xor(cdel2, 16, 64); cdel2 += __shfl_xor(cdel2, 32, 64);
        pj2   += __shfl_xor(pj2, 16, 64);   pj2   += __shfl_xor(pj2, 32, 64);

        if (g == 0) {
            res_st[it][ch][l15] = sqrtf(res2);
            fix_st[it][ch][l15] = sqrtf(pj2) + sqrtf(ds2) + sqrtf(cdel2);
        }
    }

    // ---- outputs ----
    {
        float4 o; o.x = c4[0]; o.y = c4[1]; o.z = c4[2]; o.w = c4[3];
        *(float4*)(out + ch*(BATCH*NVARS) + row*16 + 4*g) = o;
    }
    __syncthreads();
    for (int f = tid; f < 240; f += 192) {
        int it = f / 16, r = f % 16;
        out[OUT_PST + it*BATCH + blockIdx.x*16 + r] =
            res_st[it][0][r] + res_st[it][1][r] + res_st[it][2][r];
        out[OUT_FST + it*BATCH + blockIdx.x*16 + r] =
            fix_st[it][0][r] + fix_st[it][1][r] + fix_st[it][2][r];
    }
    if (tid < 16) {
        float s = 0.f;
        for (int it = 0; it < ITERS; ++it)
            s += res_st[it][0][tid] + res_st[it][1][tid] + res_st[it][2][tid];
        out[OUT_ACCP + blockIdx.x*16 + tid] = s * (1.f / 15.f);
    } else if (tid < 32) {
        int r = tid - 16;
        float s = 0.f;
        for (int it = 0; it < ITERS; ++it)
            s += fix_st[it][0][r] + fix_st[it][1][r] + fix_st[it][2][r];
        out[OUT_ACCF + blockIdx.x*16 + r] = s * (1.f / 15.f);
    }
}

extern "C" void kernel_launch(void* const* d_in, const int* in_sizes, int n_in,
                              void* d_out, int out_size, void* d_ws, size_t ws_size,
                              hipStream_t stream)
{
    const float* P    = (const float*)d_in[0];
    const float* Pdm  = (const float*)d_in[1];
    const float* Pddm = (const float*)d_in[2];
    const float* lamv = (const float*)d_in[3];
    const float* lamp = (const float*)d_in[4];
    const float* lamr = (const float*)d_in[5];
    const float* cinv = (const float*)d_in[6];
    const float* cinp = (const float*)d_in[7];
    const float* cinr = (const float*)d_in[8];
    const float* beqv = (const float*)d_in[9];
    const float* beqp = (const float*)d_in[10];
    const float* beqr = (const float*)d_in[11];
    const float* c0v  = (const float*)d_in[12];
    const float* c0p  = (const float*)d_in[13];
    const float* c0r  = (const float*)d_in[14];
    float* ws = (float*)d_ws;

    prep_kernel<<<1, 648, 0, stream>>>(P, Pdm, Pddm, ws);
    solve_kernel<<<512, 192, 0, stream>>>(P, Pdm, Pddm,
        lamv, lamp, lamr, cinv, cinp, cinr,
        beqv, beqp, beqr, c0v, c0p, c0r,
        (float*)d_out, ws);
}

// Round 24
// 110.223 us; speedup vs baseline: 5.8675x; 1.0203x over previous
//
#include <hip/hip_runtime.h>

#define NUMS   128
#define NVARS  16
#define BATCH  8192
#define ITERS  15

#define OUT_ACCF (3*BATCH*NVARS)
#define OUT_ACCP (OUT_ACCF + BATCH)
#define OUT_PST  (OUT_ACCP + BATCH)
#define OUT_FST  (OUT_PST + ITERS*BATCH)

typedef _Float16 f16;
typedef f16  f16x8 __attribute__((ext_vector_type(8)));
typedef float f32x4 __attribute__((ext_vector_type(4)));
typedef __fp16 hv2 __attribute__((ext_vector_type(2)));

// ---------------------------------------------------------------------------
// prep (unchanged): ws [0,324) = M (18x18) f32; [324,596) = Q padded [16][17]
// ---------------------------------------------------------------------------
__global__ void prep_kernel(const float* __restrict__ P, const float* __restrict__ Pd,
                            const float* __restrict__ Pdd, float* __restrict__ ws)
{
    __shared__ double GA[18][36];
    __shared__ float  ata[16][16];
    __shared__ double piv_s;
    const int t = threadIdx.x;

    if (t < 256) {
        int j = t >> 4, k = t & 15;
        float s = 0.f;
        for (int i = 0; i < NUMS; ++i)
            s += P[i*16+j]*P[i*16+k] + Pd[i*16+j]*Pd[i*16+k] + Pdd[i*16+j]*Pdd[i*16+k];
        ata[j][k] = 2.f * s;
    }
    __syncthreads();

    const int gi = t / 36, gj = t % 36;
    {
        double v;
        if (gj < 18) {
            if (gi < 16 && gj < 16)      v = (gi == gj ? 1.0 : 0.0) + (double)ata[gi][gj];
            else if (gi < 16)            v = (gj == 16) ? (double)P[gi] : (double)Pd[gi];
            else if (gj < 16)            v = (gi == 16) ? (double)P[gj] : (double)Pd[gj];
            else                         v = 0.0;
        } else {
            v = ((gj - 18) == gi) ? 1.0 : 0.0;
        }
        GA[gi][gj] = v;
    }
    __syncthreads();

    for (int k = 0; k < 18; ++k) {
        if (t == 0) piv_s = GA[k][k];
        __syncthreads();
        if (gi == k) GA[gi][gj] /= piv_s;
        __syncthreads();
        double f  = GA[gi][k];
        double rk = GA[k][gj];
        __syncthreads();
        if (gi != k) GA[gi][gj] -= f * rk;
        __syncthreads();
    }

    if (gj >= 18) ws[gi*18 + (gj - 18)] = (float)GA[gi][gj];
    if (t < 256)  ws[324 + (t >> 4)*17 + (t & 15)] = ata[t >> 4][t & 15];
    if (t >= 256 && t < 272) ws[324 + (t - 256)*17 + 16] = 0.f;
}

__device__ __forceinline__ hv2 pkh2(float a, float b) {
    return __builtin_amdgcn_cvt_pkrtz(a, b);
}
__device__ __forceinline__ unsigned h2u(hv2 h) {
    unsigned u; __builtin_memcpy(&u, &h, 4); return u;
}
__device__ __forceinline__ unsigned pkh(float a, float b) {
    return h2u(pkh2(a, b));
}
__device__ __forceinline__ f16x8 frg(uint4 u) {
    f16x8 r; __builtin_memcpy(&r, &u, 16); return r;
}
__device__ __forceinline__ f32x4 mfma16(f16x8 a, f16x8 b, f32x4 c) {
    return __builtin_amdgcn_mfma_f32_16x16x32_f16(a, b, c, 0, 0, 0);
}

// ---------------------------------------------------------------------------
// MFMA solver, shuffle-free k-map (R23, 112.5us) + CACHED PACKED SLACKS.
// R23 audit: CLIPP spent 4 of 17 pk-ops recomputing old slacks (xo,spo,yo,smo)
// from stored uo. Now spn/smn are stored packed (sp2/sm2, 2 hv2/pair) and read
// directly next iter: CLIPP 17 -> 13 ops (-18% total VALU). +48 VGPR is free:
// occupancy is grid-limited (512 blocks = 6 waves/CU; 204 VGPR still allows 8).
// Mf pre-scaled by 16 at staging (all 18 cols scale uniformly) - kills cn*16.
// ---------------------------------------------------------------------------
__launch_bounds__(192, 1)
__global__ void solve_kernel(
    const float* __restrict__ P,    const float* __restrict__ Pd,   const float* __restrict__ Pdd,
    const float* __restrict__ lamv, const float* __restrict__ lamp, const float* __restrict__ lamr,
    const float* __restrict__ cinv, const float* __restrict__ cinp, const float* __restrict__ cinr,
    const float* __restrict__ beqv, const float* __restrict__ beqp, const float* __restrict__ beqr,
    const float* __restrict__ c0v,  const float* __restrict__ c0p,  const float* __restrict__ c0r,
    float* __restrict__ out, const float* __restrict__ ws)
{
    __shared__ __align__(16) uint4 Af1[24*64];   // GEMM1 A-frags (u = A c), 24KB
    __shared__ __align__(16) uint4 Af2[12*64];   // GEMM2 A-frags (pj = A^T h), 12KB
    __shared__ float res_st[ITERS][3][16];
    __shared__ float fix_st[ITERS][3][16];

    const int tid = threadIdx.x;

    // ---- stage A-fragments with the D-layout-matched k-map ----
    for (int idx = tid; idx < 24*64; idx += 192) {
        int t = idx >> 6, l = idx & 63;
        int m = t >> 3;
        const float* src = (m == 0) ? P : (m == 1) ? Pd : Pdd;
        int cc = ((t & 7) << 4) + (l & 15);
        int gg = l >> 4;
        f16 v[8];
#pragma unroll
        for (int e = 0; e < 8; ++e)
            v[e] = (e < 4) ? (f16)src[cc*16 + 4*gg + e] : (f16)0.f;
        uint4 u; __builtin_memcpy(&u, v, 16);
        Af1[idx] = u;
    }
    for (int idx = tid; idx < 12*64; idx += 192) {
        int q = idx >> 6, l = idx & 63;
        int m = q >> 2;
        const float* src = (m == 0) ? P : (m == 1) ? Pd : Pdd;
        int gg = l >> 4;
        int var = l & 15;
        f16 v[8];
#pragma unroll
        for (int e = 0; e < 8; ++e) {
            int tile = e >> 2;
            int cc = ((q & 3) << 5) + tile*16 + 4*gg + (e & 3);
            v[e] = (f16)src[cc*16 + var];
        }
        uint4 u; __builtin_memcpy(&u, v, 16);
        Af2[idx] = u;
    }

    const int l   = tid & 63;
    const int ch  = tid >> 6;
    const int l15 = l & 15;
    const int g   = l >> 4;
    const int row = blockIdx.x * 16 + l15;

    // M (pre-scaled x16) and Q fragments; same k-map as B packs
    f16x8 Mf, Qf;
    {
        f16 mv[8], qv[8];
#pragma unroll
        for (int e = 0; e < 8; ++e) { mv[e] = (f16)0.f; qv[e] = (f16)0.f; }
#pragma unroll
        for (int e = 0; e < 4; ++e) {
            int k = 4*g + e;
            mv[e] = (f16)(16.f * ws[l15*18 + k]);
            qv[e] = (f16)ws[324 + l15*17 + k];
        }
        if (g == 0) {
            mv[4] = (f16)(16.f * ws[l15*18 + 16]);
            mv[5] = (f16)(16.f * ws[l15*18 + 17]);
        }
        __builtin_memcpy(&Mf, mv, 16);
        __builtin_memcpy(&Qf, qv, 16);
    }
    __syncthreads();

    const float* lam_p = (ch == 0) ? lamv : (ch == 1) ? lamp : lamr;
    const float* cin_p = (ch == 0) ? cinv : (ch == 1) ? cinp : cinr;
    const float* beq_p = (ch == 0) ? beqv : (ch == 1) ? beqp : beqr;
    const float* c0_p  = (ch == 0) ? c0v  : (ch == 1) ? c0p  : c0r;

    float bmx[3], bmn[3];
    bmx[0] = (ch == 0) ? 20.f : (ch == 1) ? 0.2f  : 0.25f;
    bmn[0] = (ch == 0) ? 12.f : (ch == 1) ? -0.2f : -0.25f;
    bmx[1] = (ch == 0) ? 3.f  : 0.25f;
    bmn[1] = (ch == 0) ? -3.f : -0.25f;
    bmx[2] = (ch == 0) ? 3.f  : 0.15f;
    bmn[2] = (ch == 0) ? -3.f : -0.15f;

    hv2 bmax2h[3], bmin2h[3];
#pragma unroll
    for (int m = 0; m < 3; ++m) {
        bmax2h[m] = pkh2(bmx[m], bmx[m]);
        bmin2h[m] = pkh2(bmn[m], bmn[m]);
    }
    const hv2 z2 = pkh2(0.f, 0.f);

    // ---- state: lane (g,l15) holds [row=l15][vars 4g..4g+3] ----
    f32x4 L4, c4, cq4, pj4;
    const float beq0 = beq_p[row*2], beq1 = beq_p[row*2 + 1];
    {
        float4 a = *(const float4*)(lam_p + row*16 + 4*g);
        float4 b = *(const float4*)(cin_p + row*16 + 4*g);
        L4 = (f32x4){a.x + b.x, a.y + b.y, a.z + b.z, a.w + b.w};
        float4 c0 = *(const float4*)(c0_p + row*16 + 4*g);
        c4 = (f32x4){c0.x, c0.y, c0.z, c0.w};
    }
    hv2 sp2[24][2], sm2[24][2];          // cached packed slacks (s+ and s-)
    const f32x4 zero4 = {0.f, 0.f, 0.f, 0.f};
    const float S = 0.0625f;

// init clip: compute h, store slacks (no res/ds)
#define CLIPI(u2_, h2_, qq_, ii_) { \
    hv2 x2_ = (u2_) - bmax2, rvp2_ = __builtin_elementwise_max(x2_, z2); \
    hv2 y2_ = (u2_) - bmin2, smn2_ = __builtin_elementwise_max(y2_, z2); \
    hv2 rvm2_ = smn2_ - y2_; \
    (h2_) = rvp2_ - rvm2_; \
    sp2[qq_][ii_] = rvp2_ - x2_; \
    sm2[qq_][ii_] = smn2_; }

// iter clip: slacks read from cache, updated in place
#define CLIPN(u2_, h2_, qq_, ii_) { \
    hv2 x2_ = (u2_) - bmax2, rvp2_ = __builtin_elementwise_max(x2_, z2); \
    hv2 spn2_ = rvp2_ - x2_; \
    hv2 y2_ = (u2_) - bmin2, smn2_ = __builtin_elementwise_max(y2_, z2); \
    hv2 rvm2_ = smn2_ - y2_; \
    ra2 += rvp2_*rvp2_ + rvm2_*rvm2_; \
    (h2_) = rvp2_ - rvm2_; \
    hv2 e1_ = spn2_ - sp2[qq_][ii_], e2_ = smn2_ - sm2[qq_][ii_]; \
    da2 += e1_*e1_ + e2_*e2_; \
    sp2[qq_][ii_] = spn2_; \
    sm2[qq_][ii_] = smn2_; }

    // ---- init pass: cq0, slacks0, pj0 from c0 ----
    {
        uint4 bc; bc.x = pkh(c4[0], c4[1]); bc.y = pkh(c4[2], c4[3]); bc.z = 0u; bc.w = 0u;
        f16x8 bcf = frg(bc);
        cq4 = mfma16(Qf, bcf, zero4);
        f32x4 pja0 = zero4, pja1 = zero4;
#pragma unroll
        for (int q = 0; q < 12; ++q) {
            const hv2 bmax2 = bmax2h[q >> 2], bmin2 = bmin2h[q >> 2];
            f32x4 ua = mfma16(frg(Af1[(2*q)*64 + l]), bcf, zero4);
            f32x4 ub = mfma16(frg(Af1[(2*q+1)*64 + l]), bcf, zero4);
            hv2 ua01 = pkh2(ua[0], ua[1]), ua23 = pkh2(ua[2], ua[3]);
            hv2 ub01 = pkh2(ub[0], ub[1]), ub23 = pkh2(ub[2], ub[3]);
            hv2 h2a0, h2a1, h2b0, h2b1;
            CLIPI(ua01, h2a0, 2*q, 0)   CLIPI(ua23, h2a1, 2*q, 1)
            CLIPI(ub01, h2b0, 2*q+1, 0) CLIPI(ub23, h2b1, 2*q+1, 1)
            uint4 bh;
            bh.x = h2u(h2a0); bh.y = h2u(h2a1); bh.z = h2u(h2b0); bh.w = h2u(h2b1);
            if (q & 1) pja1 = mfma16(frg(Af2[q*64 + l]), frg(bh), pja1);
            else       pja0 = mfma16(frg(Af2[q*64 + l]), frg(bh), pja0);
        }
        pj4 = pja0 + pja1;
    }

    // ---- 15 ADMM iterations ----
    for (int it = 0; it < ITERS; ++it) {
        // KKT: c_new = (16M)(rhs/16) with eq-cols folded; Mf pre-scaled
        f32x4 r4 = L4 + cq4 - pj4;
        uint4 br;
        br.x = pkh(r4[0]*S, r4[1]*S);
        br.y = pkh(r4[2]*S, r4[3]*S);
        br.z = (g == 0) ? pkh(beq0*S, beq1*S) : 0u;
        br.w = 0u;
        f32x4 cn = mfma16(Mf, frg(br), zero4);
        f32x4 cd = cn - c4;
        float cdel2 = cd[0]*cd[0] + cd[1]*cd[1] + cd[2]*cd[2] + cd[3]*cd[3];
        c4 = cn;

        uint4 bc; bc.x = pkh(c4[0], c4[1]); bc.y = pkh(c4[2], c4[3]); bc.z = 0u; bc.w = 0u;
        f16x8 bcf = frg(bc);
        cq4 = mfma16(Qf, bcf, zero4);

        float res2 = 0.f, ds2 = 0.f;
        f32x4 pja0 = zero4, pja1 = zero4;
#pragma unroll
        for (int q = 0; q < 12; ++q) {
            const hv2 bmax2 = bmax2h[q >> 2], bmin2 = bmin2h[q >> 2];
            f32x4 ua = mfma16(frg(Af1[(2*q)*64 + l]), bcf, zero4);
            f32x4 ub = mfma16(frg(Af1[(2*q+1)*64 + l]), bcf, zero4);
            hv2 ua01 = pkh2(ua[0], ua[1]), ua23 = pkh2(ua[2], ua[3]);
            hv2 ub01 = pkh2(ub[0], ub[1]), ub23 = pkh2(ub[2], ub[3]);
            hv2 ra2 = z2, da2 = z2;
            hv2 h2a0, h2a1, h2b0, h2b1;
            CLIPN(ua01, h2a0, 2*q, 0)   CLIPN(ua23, h2a1, 2*q, 1)
            CLIPN(ub01, h2b0, 2*q+1, 0) CLIPN(ub23, h2b1, 2*q+1, 1)
            res2 += (float)ra2[0] + (float)ra2[1];
            ds2  += (float)da2[0] + (float)da2[1];
            uint4 bh;
            bh.x = h2u(h2a0); bh.y = h2u(h2a1); bh.z = h2u(h2b0); bh.w = h2u(h2b1);
            if (q & 1) pja1 = mfma16(frg(Af2[q*64 + l]), frg(bh), pja1);
            else       pja0 = mfma16(frg(Af2[q*64 + l]), frg(bh), pja0);
        }
        pj4 = pja0 + pja1;
        float pj2 = pj4[0]*pj4[0] + pj4[1]*pj4[1] + pj4[2]*pj4[2] + pj4[3]*pj4[3];
        L4 = L4 - pj4;

        // all-reduce the 4 scalars over the 4 lane-groups (same batch row)
        res2  += __shfl_xor(res2, 16, 64);  res2  += __shfl_xor(res2, 32, 64);
        ds2   += __shfl_xor(ds2, 16, 64);   ds2   += __shfl_xor(ds2, 32, 64);
        cdel2 += __shfl_xor(cdel2, 16, 64); cdel2 += __shfl_xor(cdel2, 32, 64);
        pj2   += __shfl_xor(pj2, 16, 64);   pj2   += __shfl_xor(pj2, 32, 64);

        if (g == 0) {
            res_st[it][ch][l15] = sqrtf(res2);
            fix_st[it][ch][l15] = sqrtf(pj2) + sqrtf(ds2) + sqrtf(cdel2);
        }
    }

    // ---- outputs ----
    {
        float4 o; o.x = c4[0]; o.y = c4[1]; o.z = c4[2]; o.w = c4[3];
        *(float4*)(out + ch*(BATCH*NVARS) + row*16 + 4*g) = o;
    }
    __syncthreads();
    for (int f = tid; f < 240; f += 192) {
        int it = f / 16, r = f % 16;
        out[OUT_PST + it*BATCH + blockIdx.x*16 + r] =
            res_st[it][0][r] + res_st[it][1][r] + res_st[it][2][r];
        out[OUT_FST + it*BATCH + blockIdx.x*16 + r] =
            fix_st[it][0][r] + fix_st[it][1][r] + fix_st[it][2][r];
    }
    if (tid < 16) {
        float s = 0.f;
        for (int it = 0; it < ITERS; ++it)
            s += res_st[it][0][tid] + res_st[it][1][tid] + res_st[it][2][tid];
        out[OUT_ACCP + blockIdx.x*16 + tid] = s * (1.f / 15.f);
    } else if (tid < 32) {
        int r = tid - 16;
        float s = 0.f;
        for (int it = 0; it < ITERS; ++it)
            s += fix_st[it][0][r] + fix_st[it][1][r] + fix_st[it][2][r];
        out[OUT_ACCF + blockIdx.x*16 + r] = s * (1.f / 15.f);
    }
}

extern "C" void kernel_launch(void* const* d_in, const int* in_sizes, int n_in,
                              void* d_out, int out_size, void* d_ws, size_t ws_size,
                              hipStream_t stream)
{
    const float* P    = (const float*)d_in[0];
    const float* Pdm  = (const float*)d_in[1];
    const float* Pddm = (const float*)d_in[2];
    const float* lamv = (const float*)d_in[3];
    const float* lamp = (const float*)d_in[4];
    const float* lamr = (const float*)d_in[5];
    const float* cinv = (const float*)d_in[6];
    const float* cinp = (const float*)d_in[7];
    const float* cinr = (const float*)d_in[8];
    const float* beqv = (const float*)d_in[9];
    const float* beqp = (const float*)d_in[10];
    const float* beqr = (const float*)d_in[11];
    const float* c0v  = (const float*)d_in[12];
    const float* c0p  = (const float*)d_in[13];
    const float* c0r  = (const float*)d_in[14];
    float* ws = (float*)d_ws;

    prep_kernel<<<1, 648, 0, stream>>>(P, Pdm, Pddm, ws);
    solve_kernel<<<512, 192, 0, stream>>>(P, Pdm, Pddm,
        lamv, lamp, lamr, cinv, cinp, cinr,
        beqv, beqp, beqr, c0v, c0p, c0r,
        (float*)d_out, ws);
}

// Round 25
// 101.100 us; speedup vs baseline: 6.3969x; 1.0902x over previous
//
#include <hip/hip_runtime.h>

#define NUMS   128
#define NVARS  16
#define BATCH  8192
#define ITERS  15

#define OUT_ACCF (3*BATCH*NVARS)
#define OUT_ACCP (OUT_ACCF + BATCH)
#define OUT_PST  (OUT_ACCP + BATCH)
#define OUT_FST  (OUT_PST + ITERS*BATCH)

typedef _Float16 f16;
typedef f16  f16x8 __attribute__((ext_vector_type(8)));
typedef float f32x4 __attribute__((ext_vector_type(4)));
typedef __fp16 hv2 __attribute__((ext_vector_type(2)));

// ---------------------------------------------------------------------------
// prep (unchanged): ws [0,324) = M (18x18) f32; [324,596) = Q padded [16][17]
// ---------------------------------------------------------------------------
__global__ void prep_kernel(const float* __restrict__ P, const float* __restrict__ Pd,
                            const float* __restrict__ Pdd, float* __restrict__ ws)
{
    __shared__ double GA[18][36];
    __shared__ float  ata[16][16];
    __shared__ double piv_s;
    const int t = threadIdx.x;

    if (t < 256) {
        int j = t >> 4, k = t & 15;
        float s = 0.f;
        for (int i = 0; i < NUMS; ++i)
            s += P[i*16+j]*P[i*16+k] + Pd[i*16+j]*Pd[i*16+k] + Pdd[i*16+j]*Pdd[i*16+k];
        ata[j][k] = 2.f * s;
    }
    __syncthreads();

    const int gi = t / 36, gj = t % 36;
    {
        double v;
        if (gj < 18) {
            if (gi < 16 && gj < 16)      v = (gi == gj ? 1.0 : 0.0) + (double)ata[gi][gj];
            else if (gi < 16)            v = (gj == 16) ? (double)P[gi] : (double)Pd[gi];
            else if (gj < 16)            v = (gi == 16) ? (double)P[gj] : (double)Pd[gj];
            else                         v = 0.0;
        } else {
            v = ((gj - 18) == gi) ? 1.0 : 0.0;
        }
        GA[gi][gj] = v;
    }
    __syncthreads();

    for (int k = 0; k < 18; ++k) {
        if (t == 0) piv_s = GA[k][k];
        __syncthreads();
        if (gi == k) GA[gi][gj] /= piv_s;
        __syncthreads();
        double f  = GA[gi][k];
        double rk = GA[k][gj];
        __syncthreads();
        if (gi != k) GA[gi][gj] -= f * rk;
        __syncthreads();
    }

    if (gj >= 18) ws[gi*18 + (gj - 18)] = (float)GA[gi][gj];
    if (t < 256)  ws[324 + (t >> 4)*17 + (t & 15)] = ata[t >> 4][t & 15];
    if (t >= 256 && t < 272) ws[324 + (t - 256)*17 + 16] = 0.f;
}

__device__ __forceinline__ hv2 pkh2(float a, float b) {
    return __builtin_amdgcn_cvt_pkrtz(a, b);
}
__device__ __forceinline__ unsigned h2u(hv2 h) {
    unsigned u; __builtin_memcpy(&u, &h, 4); return u;
}
__device__ __forceinline__ unsigned pkh(float a, float b) {
    return h2u(pkh2(a, b));
}
__device__ __forceinline__ f16x8 frg(uint4 u) {
    f16x8 r; __builtin_memcpy(&r, &u, 16); return r;
}
__device__ __forceinline__ f32x4 mfma16(f16x8 a, f16x8 b, f32x4 c) {
    return __builtin_amdgcn_mfma_f32_16x16x32_f16(a, b, c, 0, 0, 0);
}

// ---------------------------------------------------------------------------
// MFMA solver, shuffle-free k-map + cached slacks (R24, 110us) + Q-SPLIT:
// R24 showed the kernel is latency-bound at the structural 1.5 waves/SIMD
// (cutting 18% of VALU ops gained 3%). Block = 384 thr = 6 waves: the two
// waves (half=0/1) of each channel split the 12 q-chunks 6/6 (halving the
// dominant clip+MFMA work per wave) and exchange per-lane partial
// {pj4, res2, ds2} via a double-buffered LDS tile with ONE barrier/iter
// (write buf b -> barrier -> read; rewrite of b at t+2 is after barrier t+1,
// so reads at t complete first). Waves 1536 -> 3072 (3/SIMD). KKT/Q/packs
// duplicated per half (cheap). Slack cache halves -> ~150 VGPR.
// ---------------------------------------------------------------------------
__launch_bounds__(384, 1)
__global__ void solve_kernel(
    const float* __restrict__ P,    const float* __restrict__ Pd,   const float* __restrict__ Pdd,
    const float* __restrict__ lamv, const float* __restrict__ lamp, const float* __restrict__ lamr,
    const float* __restrict__ cinv, const float* __restrict__ cinp, const float* __restrict__ cinr,
    const float* __restrict__ beqv, const float* __restrict__ beqp, const float* __restrict__ beqr,
    const float* __restrict__ c0v,  const float* __restrict__ c0p,  const float* __restrict__ c0r,
    float* __restrict__ out, const float* __restrict__ ws)
{
    __shared__ __align__(16) uint4 Af1[24*64];   // GEMM1 A-frags (u = A c), 24KB
    __shared__ __align__(16) uint4 Af2[12*64];   // GEMM2 A-frags (pj = A^T h), 12KB
    __shared__ float xch[2][2][3][6][64];        // [buf][half][ch][comp][lane] 36KB
    __shared__ float res_st[ITERS][3][16];
    __shared__ float fix_st[ITERS][3][16];

    const int tid = threadIdx.x;

    // ---- stage A-fragments with the D-layout-matched k-map ----
    for (int idx = tid; idx < 24*64; idx += 384) {
        int t = idx >> 6, l = idx & 63;
        int m = t >> 3;
        const float* src = (m == 0) ? P : (m == 1) ? Pd : Pdd;
        int cc = ((t & 7) << 4) + (l & 15);
        int gg = l >> 4;
        f16 v[8];
#pragma unroll
        for (int e = 0; e < 8; ++e)
            v[e] = (e < 4) ? (f16)src[cc*16 + 4*gg + e] : (f16)0.f;
        uint4 u; __builtin_memcpy(&u, v, 16);
        Af1[idx] = u;
    }
    for (int idx = tid; idx < 12*64; idx += 384) {
        int q = idx >> 6, l = idx & 63;
        int m = q >> 2;
        const float* src = (m == 0) ? P : (m == 1) ? Pd : Pdd;
        int gg = l >> 4;
        int var = l & 15;
        f16 v[8];
#pragma unroll
        for (int e = 0; e < 8; ++e) {
            int tile = e >> 2;
            int cc = ((q & 3) << 5) + tile*16 + 4*gg + (e & 3);
            v[e] = (f16)src[cc*16 + var];
        }
        uint4 u; __builtin_memcpy(&u, v, 16);
        Af2[idx] = u;
    }

    const int l    = tid & 63;
    const int wid  = tid >> 6;     // wave 0..5
    const int ch   = wid % 3;      // channel
    const int half = wid / 3;      // q-half 0/1
    const int l15  = l & 15;
    const int g    = l >> 4;
    const int row  = blockIdx.x * 16 + l15;
    const int QB   = half * 6;     // this wave's q range: QB..QB+5

    // M (pre-scaled x16) and Q fragments; same k-map as B packs
    f16x8 Mf, Qf;
    {
        f16 mv[8], qv[8];
#pragma unroll
        for (int e = 0; e < 8; ++e) { mv[e] = (f16)0.f; qv[e] = (f16)0.f; }
#pragma unroll
        for (int e = 0; e < 4; ++e) {
            int k = 4*g + e;
            mv[e] = (f16)(16.f * ws[l15*18 + k]);
            qv[e] = (f16)ws[324 + l15*17 + k];
        }
        if (g == 0) {
            mv[4] = (f16)(16.f * ws[l15*18 + 16]);
            mv[5] = (f16)(16.f * ws[l15*18 + 17]);
        }
        __builtin_memcpy(&Mf, mv, 16);
        __builtin_memcpy(&Qf, qv, 16);
    }
    __syncthreads();

    const float* lam_p = (ch == 0) ? lamv : (ch == 1) ? lamp : lamr;
    const float* cin_p = (ch == 0) ? cinv : (ch == 1) ? cinp : cinr;
    const float* beq_p = (ch == 0) ? beqv : (ch == 1) ? beqp : beqr;
    const float* c0_p  = (ch == 0) ? c0v  : (ch == 1) ? c0p  : c0r;

    float bmx[3], bmn[3];
    bmx[0] = (ch == 0) ? 20.f : (ch == 1) ? 0.2f  : 0.25f;
    bmn[0] = (ch == 0) ? 12.f : (ch == 1) ? -0.2f : -0.25f;
    bmx[1] = (ch == 0) ? 3.f  : 0.25f;
    bmn[1] = (ch == 0) ? -3.f : -0.25f;
    bmx[2] = (ch == 0) ? 3.f  : 0.15f;
    bmn[2] = (ch == 0) ? -3.f : -0.15f;

    const hv2 bmax2h0 = pkh2(bmx[0], bmx[0]), bmin2h0 = pkh2(bmn[0], bmn[0]);
    const hv2 bmax2h1 = pkh2(bmx[1], bmx[1]), bmin2h1 = pkh2(bmn[1], bmn[1]);
    const hv2 bmax2h2 = pkh2(bmx[2], bmx[2]), bmin2h2 = pkh2(bmn[2], bmn[2]);
    const hv2 z2 = pkh2(0.f, 0.f);

    // ---- state: lane (g,l15) holds [row=l15][vars 4g..4g+3] ----
    f32x4 L4, c4, cq4, pj4;
    const float beq0 = beq_p[row*2], beq1 = beq_p[row*2 + 1];
    {
        float4 a = *(const float4*)(lam_p + row*16 + 4*g);
        float4 b = *(const float4*)(cin_p + row*16 + 4*g);
        L4 = (f32x4){a.x + b.x, a.y + b.y, a.z + b.z, a.w + b.w};
        float4 c0 = *(const float4*)(c0_p + row*16 + 4*g);
        c4 = (f32x4){c0.x, c0.y, c0.z, c0.w};
    }
    hv2 sp2[12][2], sm2[12][2];          // cached packed slacks (this half's qs)
    const f32x4 zero4 = {0.f, 0.f, 0.f, 0.f};
    const float S = 0.0625f;

#define CLIPI(u2_, h2_, qq_, ii_) { \
    hv2 x2_ = (u2_) - bmax2, rvp2_ = __builtin_elementwise_max(x2_, z2); \
    hv2 y2_ = (u2_) - bmin2, smn2_ = __builtin_elementwise_max(y2_, z2); \
    hv2 rvm2_ = smn2_ - y2_; \
    (h2_) = rvp2_ - rvm2_; \
    sp2[qq_][ii_] = rvp2_ - x2_; \
    sm2[qq_][ii_] = smn2_; }

#define CLIPN(u2_, h2_, qq_, ii_) { \
    hv2 x2_ = (u2_) - bmax2, rvp2_ = __builtin_elementwise_max(x2_, z2); \
    hv2 spn2_ = rvp2_ - x2_; \
    hv2 y2_ = (u2_) - bmin2, smn2_ = __builtin_elementwise_max(y2_, z2); \
    hv2 rvm2_ = smn2_ - y2_; \
    ra2 += rvp2_*rvp2_ + rvm2_*rvm2_; \
    (h2_) = rvp2_ - rvm2_; \
    hv2 e1_ = spn2_ - sp2[qq_][ii_], e2_ = smn2_ - sm2[qq_][ii_]; \
    da2 += e1_*e1_ + e2_*e2_; \
    sp2[qq_][ii_] = spn2_; \
    sm2[qq_][ii_] = smn2_; }

    // ---- init pass: cq0, slacks0, pj0 (this half's qs) + exchange ----
    {
        uint4 bc; bc.x = pkh(c4[0], c4[1]); bc.y = pkh(c4[2], c4[3]); bc.z = 0u; bc.w = 0u;
        f16x8 bcf = frg(bc);
        cq4 = mfma16(Qf, bcf, zero4);
        f32x4 pja0 = zero4, pja1 = zero4;
#pragma unroll
        for (int qi = 0; qi < 6; ++qi) {
            const int q = QB + qi;
            const int m = q >> 2;
            const hv2 bmax2 = (m == 0) ? bmax2h0 : (m == 1) ? bmax2h1 : bmax2h2;
            const hv2 bmin2 = (m == 0) ? bmin2h0 : (m == 1) ? bmin2h1 : bmin2h2;
            f32x4 ua = mfma16(frg(Af1[(2*q)*64 + l]), bcf, zero4);
            f32x4 ub = mfma16(frg(Af1[(2*q+1)*64 + l]), bcf, zero4);
            hv2 ua01 = pkh2(ua[0], ua[1]), ua23 = pkh2(ua[2], ua[3]);
            hv2 ub01 = pkh2(ub[0], ub[1]), ub23 = pkh2(ub[2], ub[3]);
            hv2 h2a0, h2a1, h2b0, h2b1;
            CLIPI(ua01, h2a0, 2*qi, 0)   CLIPI(ua23, h2a1, 2*qi, 1)
            CLIPI(ub01, h2b0, 2*qi+1, 0) CLIPI(ub23, h2b1, 2*qi+1, 1)
            uint4 bh;
            bh.x = h2u(h2a0); bh.y = h2u(h2a1); bh.z = h2u(h2b0); bh.w = h2u(h2b1);
            if (qi & 1) pja1 = mfma16(frg(Af2[q*64 + l]), frg(bh), pja1);
            else        pja0 = mfma16(frg(Af2[q*64 + l]), frg(bh), pja0);
        }
        f32x4 pjp = pja0 + pja1;
        xch[0][half][ch][0][l] = pjp[0];
        xch[0][half][ch][1][l] = pjp[1];
        xch[0][half][ch][2][l] = pjp[2];
        xch[0][half][ch][3][l] = pjp[3];
        __syncthreads();
        const int oh = 1 - half;
        pj4[0] = pjp[0] + xch[0][oh][ch][0][l];
        pj4[1] = pjp[1] + xch[0][oh][ch][1][l];
        pj4[2] = pjp[2] + xch[0][oh][ch][2][l];
        pj4[3] = pjp[3] + xch[0][oh][ch][3][l];
    }

    // ---- 15 ADMM iterations ----
    for (int it = 0; it < ITERS; ++it) {
        // KKT: c_new = (16M)(rhs/16) with eq-cols folded (Mf pre-scaled)
        f32x4 r4 = L4 + cq4 - pj4;
        uint4 br;
        br.x = pkh(r4[0]*S, r4[1]*S);
        br.y = pkh(r4[2]*S, r4[3]*S);
        br.z = (g == 0) ? pkh(beq0*S, beq1*S) : 0u;
        br.w = 0u;
        f32x4 cn = mfma16(Mf, frg(br), zero4);
        f32x4 cd = cn - c4;
        float cdel2 = cd[0]*cd[0] + cd[1]*cd[1] + cd[2]*cd[2] + cd[3]*cd[3];
        c4 = cn;

        uint4 bc; bc.x = pkh(c4[0], c4[1]); bc.y = pkh(c4[2], c4[3]); bc.z = 0u; bc.w = 0u;
        f16x8 bcf = frg(bc);
        cq4 = mfma16(Qf, bcf, zero4);

        float res2 = 0.f, ds2 = 0.f;
        f32x4 pja0 = zero4, pja1 = zero4;
#pragma unroll
        for (int qi = 0; qi < 6; ++qi) {
            const int q = QB + qi;
            const int m = q >> 2;
            const hv2 bmax2 = (m == 0) ? bmax2h0 : (m == 1) ? bmax2h1 : bmax2h2;
            const hv2 bmin2 = (m == 0) ? bmin2h0 : (m == 1) ? bmin2h1 : bmin2h2;
            f32x4 ua = mfma16(frg(Af1[(2*q)*64 + l]), bcf, zero4);
            f32x4 ub = mfma16(frg(Af1[(2*q+1)*64 + l]), bcf, zero4);
            hv2 ua01 = pkh2(ua[0], ua[1]), ua23 = pkh2(ua[2], ua[3]);
            hv2 ub01 = pkh2(ub[0], ub[1]), ub23 = pkh2(ub[2], ub[3]);
            hv2 ra2 = z2, da2 = z2;
            hv2 h2a0, h2a1, h2b0, h2b1;
            CLIPN(ua01, h2a0, 2*qi, 0)   CLIPN(ua23, h2a1, 2*qi, 1)
            CLIPN(ub01, h2b0, 2*qi+1, 0) CLIPN(ub23, h2b1, 2*qi+1, 1)
            res2 += (float)ra2[0] + (float)ra2[1];
            ds2  += (float)da2[0] + (float)da2[1];
            uint4 bh;
            bh.x = h2u(h2a0); bh.y = h2u(h2a1); bh.z = h2u(h2b0); bh.w = h2u(h2b1);
            if (qi & 1) pja1 = mfma16(frg(Af2[q*64 + l]), frg(bh), pja1);
            else        pja0 = mfma16(frg(Af2[q*64 + l]), frg(bh), pja0);
        }
        f32x4 pjp = pja0 + pja1;

        // ---- cross-half exchange (double-buffered, 1 barrier/iter) ----
        const int buf = (it + 1) & 1;
        xch[buf][half][ch][0][l] = pjp[0];
        xch[buf][half][ch][1][l] = pjp[1];
        xch[buf][half][ch][2][l] = pjp[2];
        xch[buf][half][ch][3][l] = pjp[3];
        xch[buf][half][ch][4][l] = res2;
        xch[buf][half][ch][5][l] = ds2;
        __syncthreads();
        const int oh = 1 - half;
        pj4[0] = pjp[0] + xch[buf][oh][ch][0][l];
        pj4[1] = pjp[1] + xch[buf][oh][ch][1][l];
        pj4[2] = pjp[2] + xch[buf][oh][ch][2][l];
        pj4[3] = pjp[3] + xch[buf][oh][ch][3][l];
        res2 += xch[buf][oh][ch][4][l];
        ds2  += xch[buf][oh][ch][5][l];

        float pj2 = pj4[0]*pj4[0] + pj4[1]*pj4[1] + pj4[2]*pj4[2] + pj4[3]*pj4[3];
        L4 = L4 - pj4;

        // all-reduce the 4 scalars over the 4 lane-groups (same batch row)
        res2  += __shfl_xor(res2, 16, 64);  res2  += __shfl_xor(res2, 32, 64);
        ds2   += __shfl_xor(ds2, 16, 64);   ds2   += __shfl_xor(ds2, 32, 64);
        cdel2 += __shfl_xor(cdel2, 16, 64); cdel2 += __shfl_xor(cdel2, 32, 64);
        pj2   += __shfl_xor(pj2, 16, 64);   pj2   += __shfl_xor(pj2, 32, 64);

        if (g == 0 && half == 0) {
            res_st[it][ch][l15] = sqrtf(res2);
            fix_st[it][ch][l15] = sqrtf(pj2) + sqrtf(ds2) + sqrtf(cdel2);
        }
    }

    // ---- outputs ----
    if (half == 0) {
        float4 o; o.x = c4[0]; o.y = c4[1]; o.z = c4[2]; o.w = c4[3];
        *(float4*)(out + ch*(BATCH*NVARS) + row*16 + 4*g) = o;
    }
    __syncthreads();
    for (int f = tid; f < 240; f += 384) {
        int it = f / 16, r = f % 16;
        out[OUT_PST + it*BATCH + blockIdx.x*16 + r] =
            res_st[it][0][r] + res_st[it][1][r] + res_st[it][2][r];
        out[OUT_FST + it*BATCH + blockIdx.x*16 + r] =
            fix_st[it][0][r] + fix_st[it][1][r] + fix_st[it][2][r];
    }
    if (tid < 16) {
        float s = 0.f;
        for (int it = 0; it < ITERS; ++it)
            s += res_st[it][0][tid] + res_st[it][1][tid] + res_st[it][2][tid];
        out[OUT_ACCP + blockIdx.x*16 + tid] = s * (1.f / 15.f);
    } else if (tid < 32) {
        int r = tid - 16;
        float s = 0.f;
        for (int it = 0; it < ITERS; ++it)
            s += fix_st[it][0][r] + fix_st[it][1][r] + fix_st[it][2][r];
        out[OUT_ACCF + blockIdx.x*16 + r] = s * (1.f / 15.f);
    }
}

extern "C" void kernel_launch(void* const* d_in, const int* in_sizes, int n_in,
                              void* d_out, int out_size, void* d_ws, size_t ws_size,
                              hipStream_t stream)
{
    const float* P    = (const float*)d_in[0];
    const float* Pdm  = (const float*)d_in[1];
    const float* Pddm = (const float*)d_in[2];
    const float* lamv = (const float*)d_in[3];
    const float* lamp = (const float*)d_in[4];
    const float* lamr = (const float*)d_in[5];
    const float* cinv = (const float*)d_in[6];
    const float* cinp = (const float*)d_in[7];
    const float* cinr = (const float*)d_in[8];
    const float* beqv = (const float*)d_in[9];
    const float* beqp = (const float*)d_in[10];
    const float* beqr = (const float*)d_in[11];
    const float* c0v  = (const float*)d_in[12];
    const float* c0p  = (const float*)d_in[13];
    const float* c0r  = (const float*)d_in[14];
    float* ws = (float*)d_ws;

    prep_kernel<<<1, 648, 0, stream>>>(P, Pdm, Pddm, ws);
    solve_kernel<<<512, 384, 0, stream>>>(P, Pdm, Pddm,
        lamv, lamp, lamr, cinv, cinp, cinr,
        beqv, beqp, beqr, c0v, c0p, c0r,
        (float*)d_out, ws);
}

// Round 26
// 90.565 us; speedup vs baseline: 7.1411x; 1.1163x over previous
//
#include <hip/hip_runtime.h>

#define NUMS   128
#define NVARS  16
#define BATCH  8192
#define ITERS  15

#define OUT_ACCF (3*BATCH*NVARS)
#define OUT_ACCP (OUT_ACCF + BATCH)
#define OUT_PST  (OUT_ACCP + BATCH)
#define OUT_FST  (OUT_PST + ITERS*BATCH)

typedef _Float16 f16;
typedef f16  f16x8 __attribute__((ext_vector_type(8)));
typedef float f32x4 __attribute__((ext_vector_type(4)));
typedef __fp16 hv2 __attribute__((ext_vector_type(2)));

// ---------------------------------------------------------------------------
// prep (unchanged): ws [0,324) = M (18x18) f32; [324,596) = Q padded [16][17]
// ---------------------------------------------------------------------------
__global__ void prep_kernel(const float* __restrict__ P, const float* __restrict__ Pd,
                            const float* __restrict__ Pdd, float* __restrict__ ws)
{
    __shared__ double GA[18][36];
    __shared__ float  ata[16][16];
    __shared__ double piv_s;
    const int t = threadIdx.x;

    if (t < 256) {
        int j = t >> 4, k = t & 15;
        float s = 0.f;
        for (int i = 0; i < NUMS; ++i)
            s += P[i*16+j]*P[i*16+k] + Pd[i*16+j]*Pd[i*16+k] + Pdd[i*16+j]*Pdd[i*16+k];
        ata[j][k] = 2.f * s;
    }
    __syncthreads();

    const int gi = t / 36, gj = t % 36;
    {
        double v;
        if (gj < 18) {
            if (gi < 16 && gj < 16)      v = (gi == gj ? 1.0 : 0.0) + (double)ata[gi][gj];
            else if (gi < 16)            v = (gj == 16) ? (double)P[gi] : (double)Pd[gi];
            else if (gj < 16)            v = (gi == 16) ? (double)P[gj] : (double)Pd[gj];
            else                         v = 0.0;
        } else {
            v = ((gj - 18) == gi) ? 1.0 : 0.0;
        }
        GA[gi][gj] = v;
    }
    __syncthreads();

    for (int k = 0; k < 18; ++k) {
        if (t == 0) piv_s = GA[k][k];
        __syncthreads();
        if (gi == k) GA[gi][gj] /= piv_s;
        __syncthreads();
        double f  = GA[gi][k];
        double rk = GA[k][gj];
        __syncthreads();
        if (gi != k) GA[gi][gj] -= f * rk;
        __syncthreads();
    }

    if (gj >= 18) ws[gi*18 + (gj - 18)] = (float)GA[gi][gj];
    if (t < 256)  ws[324 + (t >> 4)*17 + (t & 15)] = ata[t >> 4][t & 15];
    if (t >= 256 && t < 272) ws[324 + (t - 256)*17 + 16] = 0.f;
}

__device__ __forceinline__ hv2 pkh2(float a, float b) {
    return __builtin_amdgcn_cvt_pkrtz(a, b);
}
__device__ __forceinline__ unsigned h2u(hv2 h) {
    unsigned u; __builtin_memcpy(&u, &h, 4); return u;
}
__device__ __forceinline__ unsigned pkh(float a, float b) {
    return h2u(pkh2(a, b));
}
__device__ __forceinline__ f16x8 frg(uint4 u) {
    f16x8 r; __builtin_memcpy(&r, &u, 16); return r;
}
__device__ __forceinline__ f32x4 mfma16(f16x8 a, f16x8 b, f32x4 c) {
    return __builtin_amdgcn_mfma_f32_16x16x32_f16(a, b, c, 0, 0, 0);
}

// ---------------------------------------------------------------------------
// MFMA solver, shuffle-free k-map + cached slacks + 4-WAY Q-SPLIT.
// R25 (2-way split, 101us) doubled occupancy to 3 waves/SIMD but per-wave
// VALU duty was still ~17% (VALUBusy 51%) -> extend the same lever. Block =
// 768 thr = 12 waves (3 ch x 4 quarters); each wave runs 3 of 12 q-chunks;
// partial {pj4,res2,ds2} exchanged via double-buffered LDS (1 barrier/iter,
// 3-partner sum, stride-1 = conflict-free). LDS 79.5KB -> 2 blocks/CU ->
// 24 waves/CU = 6 waves/SIMD (VGPR 84: 512/84 = 6 fits). Duplicated
// KKT/Q/packs per quarter (~+11% total issue) bought 2x parallelism.
// ---------------------------------------------------------------------------
__launch_bounds__(768, 1)
__global__ void solve_kernel(
    const float* __restrict__ P,    const float* __restrict__ Pd,   const float* __restrict__ Pdd,
    const float* __restrict__ lamv, const float* __restrict__ lamp, const float* __restrict__ lamr,
    const float* __restrict__ cinv, const float* __restrict__ cinp, const float* __restrict__ cinr,
    const float* __restrict__ beqv, const float* __restrict__ beqp, const float* __restrict__ beqr,
    const float* __restrict__ c0v,  const float* __restrict__ c0p,  const float* __restrict__ c0r,
    float* __restrict__ out, const float* __restrict__ ws)
{
    __shared__ __align__(16) uint4 Af1[24*64];   // GEMM1 A-frags (u = A c), 24KB
    __shared__ __align__(16) uint4 Af2[12*64];   // GEMM2 A-frags (pj = A^T h), 12KB
    __shared__ float xch[2][4][3][6][64];        // [buf][qtr][ch][comp][lane] 36.9KB
    __shared__ float res_st[ITERS][3][16];
    __shared__ float fix_st[ITERS][3][16];

    const int tid = threadIdx.x;

    // ---- stage A-fragments with the D-layout-matched k-map ----
    for (int idx = tid; idx < 24*64; idx += 768) {
        int t = idx >> 6, l = idx & 63;
        int m = t >> 3;
        const float* src = (m == 0) ? P : (m == 1) ? Pd : Pdd;
        int cc = ((t & 7) << 4) + (l & 15);
        int gg = l >> 4;
        f16 v[8];
#pragma unroll
        for (int e = 0; e < 8; ++e)
            v[e] = (e < 4) ? (f16)src[cc*16 + 4*gg + e] : (f16)0.f;
        uint4 u; __builtin_memcpy(&u, v, 16);
        Af1[idx] = u;
    }
    for (int idx = tid; idx < 12*64; idx += 768) {
        int q = idx >> 6, l = idx & 63;
        int m = q >> 2;
        const float* src = (m == 0) ? P : (m == 1) ? Pd : Pdd;
        int gg = l >> 4;
        int var = l & 15;
        f16 v[8];
#pragma unroll
        for (int e = 0; e < 8; ++e) {
            int tile = e >> 2;
            int cc = ((q & 3) << 5) + tile*16 + 4*gg + (e & 3);
            v[e] = (f16)src[cc*16 + var];
        }
        uint4 u; __builtin_memcpy(&u, v, 16);
        Af2[idx] = u;
    }

    const int l    = tid & 63;
    const int wid  = tid >> 6;     // wave 0..11
    const int ch   = wid % 3;      // channel
    const int qtr  = wid / 3;      // q-quarter 0..3
    const int l15  = l & 15;
    const int g    = l >> 4;
    const int row  = blockIdx.x * 16 + l15;
    const int QB   = qtr * 3;      // this wave's q range: QB..QB+2

    // M (pre-scaled x16) and Q fragments; same k-map as B packs
    f16x8 Mf, Qf;
    {
        f16 mv[8], qv[8];
#pragma unroll
        for (int e = 0; e < 8; ++e) { mv[e] = (f16)0.f; qv[e] = (f16)0.f; }
#pragma unroll
        for (int e = 0; e < 4; ++e) {
            int k = 4*g + e;
            mv[e] = (f16)(16.f * ws[l15*18 + k]);
            qv[e] = (f16)ws[324 + l15*17 + k];
        }
        if (g == 0) {
            mv[4] = (f16)(16.f * ws[l15*18 + 16]);
            mv[5] = (f16)(16.f * ws[l15*18 + 17]);
        }
        __builtin_memcpy(&Mf, mv, 16);
        __builtin_memcpy(&Qf, qv, 16);
    }
    __syncthreads();

    const float* lam_p = (ch == 0) ? lamv : (ch == 1) ? lamp : lamr;
    const float* cin_p = (ch == 0) ? cinv : (ch == 1) ? cinp : cinr;
    const float* beq_p = (ch == 0) ? beqv : (ch == 1) ? beqp : beqr;
    const float* c0_p  = (ch == 0) ? c0v  : (ch == 1) ? c0p  : c0r;

    float bmx[3], bmn[3];
    bmx[0] = (ch == 0) ? 20.f : (ch == 1) ? 0.2f  : 0.25f;
    bmn[0] = (ch == 0) ? 12.f : (ch == 1) ? -0.2f : -0.25f;
    bmx[1] = (ch == 0) ? 3.f  : 0.25f;
    bmn[1] = (ch == 0) ? -3.f : -0.25f;
    bmx[2] = (ch == 0) ? 3.f  : 0.15f;
    bmn[2] = (ch == 0) ? -3.f : -0.15f;

    const hv2 bmax2h0 = pkh2(bmx[0], bmx[0]), bmin2h0 = pkh2(bmn[0], bmn[0]);
    const hv2 bmax2h1 = pkh2(bmx[1], bmx[1]), bmin2h1 = pkh2(bmn[1], bmn[1]);
    const hv2 bmax2h2 = pkh2(bmx[2], bmx[2]), bmin2h2 = pkh2(bmn[2], bmn[2]);
    const hv2 z2 = pkh2(0.f, 0.f);

    // ---- state: lane (g,l15) holds [row=l15][vars 4g..4g+3] ----
    f32x4 L4, c4, cq4, pj4;
    const float beq0 = beq_p[row*2], beq1 = beq_p[row*2 + 1];
    {
        float4 a = *(const float4*)(lam_p + row*16 + 4*g);
        float4 b = *(const float4*)(cin_p + row*16 + 4*g);
        L4 = (f32x4){a.x + b.x, a.y + b.y, a.z + b.z, a.w + b.w};
        float4 c0 = *(const float4*)(c0_p + row*16 + 4*g);
        c4 = (f32x4){c0.x, c0.y, c0.z, c0.w};
    }
    hv2 sp2[6][2], sm2[6][2];            // cached packed slacks (this quarter)
    const f32x4 zero4 = {0.f, 0.f, 0.f, 0.f};
    const float S = 0.0625f;

#define CLIPI(u2_, h2_, qq_, ii_) { \
    hv2 x2_ = (u2_) - bmax2, rvp2_ = __builtin_elementwise_max(x2_, z2); \
    hv2 y2_ = (u2_) - bmin2, smn2_ = __builtin_elementwise_max(y2_, z2); \
    hv2 rvm2_ = smn2_ - y2_; \
    (h2_) = rvp2_ - rvm2_; \
    sp2[qq_][ii_] = rvp2_ - x2_; \
    sm2[qq_][ii_] = smn2_; }

#define CLIPN(u2_, h2_, qq_, ii_) { \
    hv2 x2_ = (u2_) - bmax2, rvp2_ = __builtin_elementwise_max(x2_, z2); \
    hv2 spn2_ = rvp2_ - x2_; \
    hv2 y2_ = (u2_) - bmin2, smn2_ = __builtin_elementwise_max(y2_, z2); \
    hv2 rvm2_ = smn2_ - y2_; \
    ra2 += rvp2_*rvp2_ + rvm2_*rvm2_; \
    (h2_) = rvp2_ - rvm2_; \
    hv2 e1_ = spn2_ - sp2[qq_][ii_], e2_ = smn2_ - sm2[qq_][ii_]; \
    da2 += e1_*e1_ + e2_*e2_; \
    sp2[qq_][ii_] = spn2_; \
    sm2[qq_][ii_] = smn2_; }

    // ---- init pass: cq0, slacks0, pj0 (this quarter's qs) + exchange ----
    {
        uint4 bc; bc.x = pkh(c4[0], c4[1]); bc.y = pkh(c4[2], c4[3]); bc.z = 0u; bc.w = 0u;
        f16x8 bcf = frg(bc);
        cq4 = mfma16(Qf, bcf, zero4);
        f32x4 pja0 = zero4, pja1 = zero4;
#pragma unroll
        for (int qi = 0; qi < 3; ++qi) {
            const int q = QB + qi;
            const int m = q >> 2;
            const hv2 bmax2 = (m == 0) ? bmax2h0 : (m == 1) ? bmax2h1 : bmax2h2;
            const hv2 bmin2 = (m == 0) ? bmin2h0 : (m == 1) ? bmin2h1 : bmin2h2;
            f32x4 ua = mfma16(frg(Af1[(2*q)*64 + l]), bcf, zero4);
            f32x4 ub = mfma16(frg(Af1[(2*q+1)*64 + l]), bcf, zero4);
            hv2 ua01 = pkh2(ua[0], ua[1]), ua23 = pkh2(ua[2], ua[3]);
            hv2 ub01 = pkh2(ub[0], ub[1]), ub23 = pkh2(ub[2], ub[3]);
            hv2 h2a0, h2a1, h2b0, h2b1;
            CLIPI(ua01, h2a0, 2*qi, 0)   CLIPI(ua23, h2a1, 2*qi, 1)
            CLIPI(ub01, h2b0, 2*qi+1, 0) CLIPI(ub23, h2b1, 2*qi+1, 1)
            uint4 bh;
            bh.x = h2u(h2a0); bh.y = h2u(h2a1); bh.z = h2u(h2b0); bh.w = h2u(h2b1);
            if (qi & 1) pja1 = mfma16(frg(Af2[q*64 + l]), frg(bh), pja1);
            else        pja0 = mfma16(frg(Af2[q*64 + l]), frg(bh), pja0);
        }
        f32x4 pjp = pja0 + pja1;
        xch[0][qtr][ch][0][l] = pjp[0];
        xch[0][qtr][ch][1][l] = pjp[1];
        xch[0][qtr][ch][2][l] = pjp[2];
        xch[0][qtr][ch][3][l] = pjp[3];
        __syncthreads();
#pragma unroll
        for (int k = 0; k < 4; ++k) {
            float s = pjp[k];
#pragma unroll
            for (int o = 1; o < 4; ++o)
                s += xch[0][(qtr + o) & 3][ch][k][l];
            pj4[k] = s;
        }
    }

    // ---- 15 ADMM iterations ----
    for (int it = 0; it < ITERS; ++it) {
        // KKT: c_new = (16M)(rhs/16) with eq-cols folded (Mf pre-scaled)
        f32x4 r4 = L4 + cq4 - pj4;
        uint4 br;
        br.x = pkh(r4[0]*S, r4[1]*S);
        br.y = pkh(r4[2]*S, r4[3]*S);
        br.z = (g == 0) ? pkh(beq0*S, beq1*S) : 0u;
        br.w = 0u;
        f32x4 cn = mfma16(Mf, frg(br), zero4);
        f32x4 cd = cn - c4;
        float cdel2 = cd[0]*cd[0] + cd[1]*cd[1] + cd[2]*cd[2] + cd[3]*cd[3];
        c4 = cn;

        uint4 bc; bc.x = pkh(c4[0], c4[1]); bc.y = pkh(c4[2], c4[3]); bc.z = 0u; bc.w = 0u;
        f16x8 bcf = frg(bc);
        cq4 = mfma16(Qf, bcf, zero4);

        float res2 = 0.f, ds2 = 0.f;
        f32x4 pja0 = zero4, pja1 = zero4;
#pragma unroll
        for (int qi = 0; qi < 3; ++qi) {
            const int q = QB + qi;
            const int m = q >> 2;
            const hv2 bmax2 = (m == 0) ? bmax2h0 : (m == 1) ? bmax2h1 : bmax2h2;
            const hv2 bmin2 = (m == 0) ? bmin2h0 : (m == 1) ? bmin2h1 : bmin2h2;
            f32x4 ua = mfma16(frg(Af1[(2*q)*64 + l]), bcf, zero4);
            f32x4 ub = mfma16(frg(Af1[(2*q+1)*64 + l]), bcf, zero4);
            hv2 ua01 = pkh2(ua[0], ua[1]), ua23 = pkh2(ua[2], ua[3]);
            hv2 ub01 = pkh2(ub[0], ub[1]), ub23 = pkh2(ub[2], ub[3]);
            hv2 ra2 = z2, da2 = z2;
            hv2 h2a0, h2a1, h2b0, h2b1;
            CLIPN(ua01, h2a0, 2*qi, 0)   CLIPN(ua23, h2a1, 2*qi, 1)
            CLIPN(ub01, h2b0, 2*qi+1, 0) CLIPN(ub23, h2b1, 2*qi+1, 1)
            res2 += (float)ra2[0] + (float)ra2[1];
            ds2  += (float)da2[0] + (float)da2[1];
            uint4 bh;
            bh.x = h2u(h2a0); bh.y = h2u(h2a1); bh.z = h2u(h2b0); bh.w = h2u(h2b1);
            if (qi & 1) pja1 = mfma16(frg(Af2[q*64 + l]), frg(bh), pja1);
            else        pja0 = mfma16(frg(Af2[q*64 + l]), frg(bh), pja0);
        }
        f32x4 pjp = pja0 + pja1;

        // ---- cross-quarter exchange (double-buffered, 1 barrier/iter) ----
        const int buf = (it + 1) & 1;
        xch[buf][qtr][ch][0][l] = pjp[0];
        xch[buf][qtr][ch][1][l] = pjp[1];
        xch[buf][qtr][ch][2][l] = pjp[2];
        xch[buf][qtr][ch][3][l] = pjp[3];
        xch[buf][qtr][ch][4][l] = res2;
        xch[buf][qtr][ch][5][l] = ds2;
        __syncthreads();
#pragma unroll
        for (int k = 0; k < 4; ++k) {
            float s = pjp[k];
#pragma unroll
            for (int o = 1; o < 4; ++o)
                s += xch[buf][(qtr + o) & 3][ch][k][l];
            pj4[k] = s;
        }
#pragma unroll
        for (int o = 1; o < 4; ++o) {
            res2 += xch[buf][(qtr + o) & 3][ch][4][l];
            ds2  += xch[buf][(qtr + o) & 3][ch][5][l];
        }

        float pj2 = pj4[0]*pj4[0] + pj4[1]*pj4[1] + pj4[2]*pj4[2] + pj4[3]*pj4[3];
        L4 = L4 - pj4;

        // all-reduce the 4 scalars over the 4 lane-groups (same batch row)
        res2  += __shfl_xor(res2, 16, 64);  res2  += __shfl_xor(res2, 32, 64);
        ds2   += __shfl_xor(ds2, 16, 64);   ds2   += __shfl_xor(ds2, 32, 64);
        cdel2 += __shfl_xor(cdel2, 16, 64); cdel2 += __shfl_xor(cdel2, 32, 64);
        pj2   += __shfl_xor(pj2, 16, 64);   pj2   += __shfl_xor(pj2, 32, 64);

        if (g == 0 && qtr == 0) {
            res_st[it][ch][l15] = sqrtf(res2);
            fix_st[it][ch][l15] = sqrtf(pj2) + sqrtf(ds2) + sqrtf(cdel2);
        }
    }

    // ---- outputs ----
    if (qtr == 0) {
        float4 o; o.x = c4[0]; o.y = c4[1]; o.z = c4[2]; o.w = c4[3];
        *(float4*)(out + ch*(BATCH*NVARS) + row*16 + 4*g) = o;
    }
    __syncthreads();
    if (tid < 240) {
        int it = tid / 16, r = tid % 16;
        out[OUT_PST + it*BATCH + blockIdx.x*16 + r] =
            res_st[it][0][r] + res_st[it][1][r] + res_st[it][2][r];
        out[OUT_FST + it*BATCH + blockIdx.x*16 + r] =
            fix_st[it][0][r] + fix_st[it][1][r] + fix_st[it][2][r];
    }
    if (tid >= 256 && tid < 272) {
        int r = tid - 256;
        float s = 0.f;
        for (int it = 0; it < ITERS; ++it)
            s += res_st[it][0][r] + res_st[it][1][r] + res_st[it][2][r];
        out[OUT_ACCP + blockIdx.x*16 + r] = s * (1.f / 15.f);
    } else if (tid >= 272 && tid < 288) {
        int r = tid - 272;
        float s = 0.f;
        for (int it = 0; it < ITERS; ++it)
            s += fix_st[it][0][r] + fix_st[it][1][r] + fix_st[it][2][r];
        out[OUT_ACCF + blockIdx.x*16 + r] = s * (1.f / 15.f);
    }
}

extern "C" void kernel_launch(void* const* d_in, const int* in_sizes, int n_in,
                              void* d_out, int out_size, void* d_ws, size_t ws_size,
                              hipStream_t stream)
{
    const float* P    = (const float*)d_in[0];
    const float* Pdm  = (const float*)d_in[1];
    const float* Pddm = (const float*)d_in[2];
    const float* lamv = (const float*)d_in[3];
    const float* lamp = (const float*)d_in[4];
    const float* lamr = (const float*)d_in[5];
    const float* cinv = (const float*)d_in[6];
    const float* cinp = (const float*)d_in[7];
    const float* cinr = (const float*)d_in[8];
    const float* beqv = (const float*)d_in[9];
    const float* beqp = (const float*)d_in[10];
    const float* beqr = (const float*)d_in[11];
    const float* c0v  = (const float*)d_in[12];
    const float* c0p  = (const float*)d_in[13];
    const float* c0r  = (const float*)d_in[14];
    float* ws = (float*)d_ws;

    prep_kernel<<<1, 648, 0, stream>>>(P, Pdm, Pddm, ws);
    solve_kernel<<<512, 768, 0, stream>>>(P, Pdm, Pddm,
        lamv, lamp, lamr, cinv, cinp, cinr,
        beqv, beqp, beqr, c0v, c0p, c0r,
        (float*)d_out, ws);
}

// Round 27
// 80.646 us; speedup vs baseline: 8.0194x; 1.1230x over previous
//
#include <hip/hip_runtime.h>

#define NUMS   128
#define NVARS  16
#define BATCH  8192
#define ITERS  15

#define OUT_ACCF (3*BATCH*NVARS)
#define OUT_ACCP (OUT_ACCF + BATCH)
#define OUT_PST  (OUT_ACCP + BATCH)
#define OUT_FST  (OUT_PST + ITERS*BATCH)

typedef _Float16 f16;
typedef f16  f16x8 __attribute__((ext_vector_type(8)));
typedef float f32x4 __attribute__((ext_vector_type(4)));
typedef __fp16 hv2 __attribute__((ext_vector_type(2)));

// ---------------------------------------------------------------------------
// prep (unchanged): ws [0,324) = M (18x18) f32; [324,596) = Q padded [16][17]
// ---------------------------------------------------------------------------
__global__ void prep_kernel(const float* __restrict__ P, const float* __restrict__ Pd,
                            const float* __restrict__ Pdd, float* __restrict__ ws)
{
    __shared__ double GA[18][36];
    __shared__ float  ata[16][16];
    __shared__ double piv_s;
    const int t = threadIdx.x;

    if (t < 256) {
        int j = t >> 4, k = t & 15;
        float s = 0.f;
        for (int i = 0; i < NUMS; ++i)
            s += P[i*16+j]*P[i*16+k] + Pd[i*16+j]*Pd[i*16+k] + Pdd[i*16+j]*Pdd[i*16+k];
        ata[j][k] = 2.f * s;
    }
    __syncthreads();

    const int gi = t / 36, gj = t % 36;
    {
        double v;
        if (gj < 18) {
            if (gi < 16 && gj < 16)      v = (gi == gj ? 1.0 : 0.0) + (double)ata[gi][gj];
            else if (gi < 16)            v = (gj == 16) ? (double)P[gi] : (double)Pd[gi];
            else if (gj < 16)            v = (gi == 16) ? (double)P[gj] : (double)Pd[gj];
            else                         v = 0.0;
        } else {
            v = ((gj - 18) == gi) ? 1.0 : 0.0;
        }
        GA[gi][gj] = v;
    }
    __syncthreads();

    for (int k = 0; k < 18; ++k) {
        if (t == 0) piv_s = GA[k][k];
        __syncthreads();
        if (gi == k) GA[gi][gj] /= piv_s;
        __syncthreads();
        double f  = GA[gi][k];
        double rk = GA[k][gj];
        __syncthreads();
        if (gi != k) GA[gi][gj] -= f * rk;
        __syncthreads();
    }

    if (gj >= 18) ws[gi*18 + (gj - 18)] = (float)GA[gi][gj];
    if (t < 256)  ws[324 + (t >> 4)*17 + (t & 15)] = ata[t >> 4][t & 15];
    if (t >= 256 && t < 272) ws[324 + (t - 256)*17 + 16] = 0.f;
}

__device__ __forceinline__ hv2 pkh2(float a, float b) {
    return __builtin_amdgcn_cvt_pkrtz(a, b);
}
__device__ __forceinline__ unsigned h2u(hv2 h) {
    unsigned u; __builtin_memcpy(&u, &h, 4); return u;
}
__device__ __forceinline__ unsigned pkh(float a, float b) {
    return h2u(pkh2(a, b));
}
__device__ __forceinline__ f16x8 frg(uint4 u) {
    f16x8 r; __builtin_memcpy(&r, &u, 16); return r;
}
__device__ __forceinline__ f32x4 mfma16(f16x8 a, f16x8 b, f32x4 c) {
    return __builtin_amdgcn_mfma_f32_16x16x32_f16(a, b, c, 0, 0, 0);
}

// ---------------------------------------------------------------------------
// MFMA solver: shuffle-free k-map + cached slacks + 2-WAY SPLIT x 2 TILES.
// R26 (4-way split, 90.6us) saturated occupancy (24 waves/CU = 6/SIMD max for
// this shape) at VALUBusy 66%. This version keeps the SAME occupancy but cuts
// total issue ~14%: block = 768 thr = 12 waves = 2 row-tiles x 3 ch x 2
// halves. Per-wave 6 q-chunks -> per-quarter overhead (KKT/Q/packs/exchange)
// amortized 2x; exchange partners 3 -> 1. Af1 is half-zero by k-map, stored
// COMPACT as uint2 (24->12KB) so LDS = 12+12+36.9+11.5 = 71.3KB -> 2 blk/CU.
// ---------------------------------------------------------------------------
__launch_bounds__(768, 1)
__global__ void solve_kernel(
    const float* __restrict__ P,    const float* __restrict__ Pd,   const float* __restrict__ Pdd,
    const float* __restrict__ lamv, const float* __restrict__ lamp, const float* __restrict__ lamr,
    const float* __restrict__ cinv, const float* __restrict__ cinp, const float* __restrict__ cinr,
    const float* __restrict__ beqv, const float* __restrict__ beqp, const float* __restrict__ beqr,
    const float* __restrict__ c0v,  const float* __restrict__ c0p,  const float* __restrict__ c0r,
    float* __restrict__ out, const float* __restrict__ ws)
{
    __shared__ __align__(16) uint2 Af1c[24*64];  // GEMM1 A-frags compact, 12KB
    __shared__ __align__(16) uint4 Af2[12*64];   // GEMM2 A-frags, 12KB
    __shared__ float xch[2][2][2][3][6][64];     // [buf][tile][half][ch][comp][lane] 36.9KB
    __shared__ float res_st[ITERS][2][3][16];
    __shared__ float fix_st[ITERS][2][3][16];

    const int tid = threadIdx.x;

    // ---- stage A-fragments with the D-layout-matched k-map ----
    for (int idx = tid; idx < 24*64; idx += 768) {
        int t = idx >> 6, l = idx & 63;
        int m = t >> 3;
        const float* src = (m == 0) ? P : (m == 1) ? Pd : Pdd;
        int cc = ((t & 7) << 4) + (l & 15);
        int gg = l >> 4;
        f16 v[4];
#pragma unroll
        for (int e = 0; e < 4; ++e)
            v[e] = (f16)src[cc*16 + 4*gg + e];
        uint2 u; __builtin_memcpy(&u, v, 8);
        Af1c[idx] = u;
    }
    for (int idx = tid; idx < 12*64; idx += 768) {
        int q = idx >> 6, l = idx & 63;
        int m = q >> 2;
        const float* src = (m == 0) ? P : (m == 1) ? Pd : Pdd;
        int gg = l >> 4;
        int var = l & 15;
        f16 v[8];
#pragma unroll
        for (int e = 0; e < 8; ++e) {
            int tile = e >> 2;
            int cc = ((q & 3) << 5) + tile*16 + 4*gg + (e & 3);
            v[e] = (f16)src[cc*16 + var];
        }
        uint4 u; __builtin_memcpy(&u, v, 16);
        Af2[idx] = u;
    }

    const int l    = tid & 63;
    const int wid  = tid >> 6;     // wave 0..11
    const int tile = wid / 6;      // row-tile 0/1
    const int sub  = wid - tile*6;
    const int ch   = sub % 3;      // channel
    const int half = sub / 3;      // q-half 0/1
    const int l15  = l & 15;
    const int g    = l >> 4;
    const int row  = blockIdx.x * 32 + tile * 16 + l15;
    const int QB   = half * 6;     // this wave's q range: QB..QB+5

    // M (pre-scaled x16) and Q fragments; same k-map as B packs
    f16x8 Mf, Qf;
    {
        f16 mv[8], qv[8];
#pragma unroll
        for (int e = 0; e < 8; ++e) { mv[e] = (f16)0.f; qv[e] = (f16)0.f; }
#pragma unroll
        for (int e = 0; e < 4; ++e) {
            int k = 4*g + e;
            mv[e] = (f16)(16.f * ws[l15*18 + k]);
            qv[e] = (f16)ws[324 + l15*17 + k];
        }
        if (g == 0) {
            mv[4] = (f16)(16.f * ws[l15*18 + 16]);
            mv[5] = (f16)(16.f * ws[l15*18 + 17]);
        }
        __builtin_memcpy(&Mf, mv, 16);
        __builtin_memcpy(&Qf, qv, 16);
    }
    __syncthreads();

    const float* lam_p = (ch == 0) ? lamv : (ch == 1) ? lamp : lamr;
    const float* cin_p = (ch == 0) ? cinv : (ch == 1) ? cinp : cinr;
    const float* beq_p = (ch == 0) ? beqv : (ch == 1) ? beqp : beqr;
    const float* c0_p  = (ch == 0) ? c0v  : (ch == 1) ? c0p  : c0r;

    float bmx[3], bmn[3];
    bmx[0] = (ch == 0) ? 20.f : (ch == 1) ? 0.2f  : 0.25f;
    bmn[0] = (ch == 0) ? 12.f : (ch == 1) ? -0.2f : -0.25f;
    bmx[1] = (ch == 0) ? 3.f  : 0.25f;
    bmn[1] = (ch == 0) ? -3.f : -0.25f;
    bmx[2] = (ch == 0) ? 3.f  : 0.15f;
    bmn[2] = (ch == 0) ? -3.f : -0.15f;

    const hv2 bmax2h0 = pkh2(bmx[0], bmx[0]), bmin2h0 = pkh2(bmn[0], bmn[0]);
    const hv2 bmax2h1 = pkh2(bmx[1], bmx[1]), bmin2h1 = pkh2(bmn[1], bmn[1]);
    const hv2 bmax2h2 = pkh2(bmx[2], bmx[2]), bmin2h2 = pkh2(bmn[2], bmn[2]);
    const hv2 z2 = pkh2(0.f, 0.f);

    // ---- state: lane (g,l15) holds [row=l15][vars 4g..4g+3] ----
    f32x4 L4, c4, cq4, pj4;
    const float beq0 = beq_p[row*2], beq1 = beq_p[row*2 + 1];
    {
        float4 a = *(const float4*)(lam_p + row*16 + 4*g);
        float4 b = *(const float4*)(cin_p + row*16 + 4*g);
        L4 = (f32x4){a.x + b.x, a.y + b.y, a.z + b.z, a.w + b.w};
        float4 c0 = *(const float4*)(c0_p + row*16 + 4*g);
        c4 = (f32x4){c0.x, c0.y, c0.z, c0.w};
    }
    hv2 sp2[12][2], sm2[12][2];          // cached packed slacks (this half's qs)
    const f32x4 zero4 = {0.f, 0.f, 0.f, 0.f};
    const float S = 0.0625f;

#define CLIPI(u2_, h2_, qq_, ii_) { \
    hv2 x2_ = (u2_) - bmax2, rvp2_ = __builtin_elementwise_max(x2_, z2); \
    hv2 y2_ = (u2_) - bmin2, smn2_ = __builtin_elementwise_max(y2_, z2); \
    hv2 rvm2_ = smn2_ - y2_; \
    (h2_) = rvp2_ - rvm2_; \
    sp2[qq_][ii_] = rvp2_ - x2_; \
    sm2[qq_][ii_] = smn2_; }

#define CLIPN(u2_, h2_, qq_, ii_) { \
    hv2 x2_ = (u2_) - bmax2, rvp2_ = __builtin_elementwise_max(x2_, z2); \
    hv2 spn2_ = rvp2_ - x2_; \
    hv2 y2_ = (u2_) - bmin2, smn2_ = __builtin_elementwise_max(y2_, z2); \
    hv2 rvm2_ = smn2_ - y2_; \
    ra2 += rvp2_*rvp2_ + rvm2_*rvm2_; \
    (h2_) = rvp2_ - rvm2_; \
    hv2 e1_ = spn2_ - sp2[qq_][ii_], e2_ = smn2_ - sm2[qq_][ii_]; \
    da2 += e1_*e1_ + e2_*e2_; \
    sp2[qq_][ii_] = spn2_; \
    sm2[qq_][ii_] = smn2_; }

#define AF1(idx_) ({ uint2 p_ = Af1c[idx_]; uint4 u_; \
    u_.x = p_.x; u_.y = p_.y; u_.z = 0u; u_.w = 0u; u_; })

    // ---- init pass: cq0, slacks0, pj0 (this half's qs) + exchange ----
    {
        uint4 bc; bc.x = pkh(c4[0], c4[1]); bc.y = pkh(c4[2], c4[3]); bc.z = 0u; bc.w = 0u;
        f16x8 bcf = frg(bc);
        cq4 = mfma16(Qf, bcf, zero4);
        f32x4 pja0 = zero4, pja1 = zero4;
#pragma unroll
        for (int qi = 0; qi < 6; ++qi) {
            const int q = QB + qi;
            const int m = q >> 2;
            const hv2 bmax2 = (m == 0) ? bmax2h0 : (m == 1) ? bmax2h1 : bmax2h2;
            const hv2 bmin2 = (m == 0) ? bmin2h0 : (m == 1) ? bmin2h1 : bmin2h2;
            f32x4 ua = mfma16(frg(AF1((2*q)*64 + l)), bcf, zero4);
            f32x4 ub = mfma16(frg(AF1((2*q+1)*64 + l)), bcf, zero4);
            hv2 ua01 = pkh2(ua[0], ua[1]), ua23 = pkh2(ua[2], ua[3]);
            hv2 ub01 = pkh2(ub[0], ub[1]), ub23 = pkh2(ub[2], ub[3]);
            hv2 h2a0, h2a1, h2b0, h2b1;
            CLIPI(ua01, h2a0, 2*qi, 0)   CLIPI(ua23, h2a1, 2*qi, 1)
            CLIPI(ub01, h2b0, 2*qi+1, 0) CLIPI(ub23, h2b1, 2*qi+1, 1)
            uint4 bh;
            bh.x = h2u(h2a0); bh.y = h2u(h2a1); bh.z = h2u(h2b0); bh.w = h2u(h2b1);
            if (qi & 1) pja1 = mfma16(frg(Af2[q*64 + l]), frg(bh), pja1);
            else        pja0 = mfma16(frg(Af2[q*64 + l]), frg(bh), pja0);
        }
        f32x4 pjp = pja0 + pja1;
        xch[0][tile][half][ch][0][l] = pjp[0];
        xch[0][tile][half][ch][1][l] = pjp[1];
        xch[0][tile][half][ch][2][l] = pjp[2];
        xch[0][tile][half][ch][3][l] = pjp[3];
        __syncthreads();
        const int oh = 1 - half;
        pj4[0] = pjp[0] + xch[0][tile][oh][ch][0][l];
        pj4[1] = pjp[1] + xch[0][tile][oh][ch][1][l];
        pj4[2] = pjp[2] + xch[0][tile][oh][ch][2][l];
        pj4[3] = pjp[3] + xch[0][tile][oh][ch][3][l];
    }

    // ---- 15 ADMM iterations ----
    for (int it = 0; it < ITERS; ++it) {
        // KKT: c_new = (16M)(rhs/16) with eq-cols folded (Mf pre-scaled)
        f32x4 r4 = L4 + cq4 - pj4;
        uint4 br;
        br.x = pkh(r4[0]*S, r4[1]*S);
        br.y = pkh(r4[2]*S, r4[3]*S);
        br.z = (g == 0) ? pkh(beq0*S, beq1*S) : 0u;
        br.w = 0u;
        f32x4 cn = mfma16(Mf, frg(br), zero4);
        f32x4 cd = cn - c4;
        float cdel2 = cd[0]*cd[0] + cd[1]*cd[1] + cd[2]*cd[2] + cd[3]*cd[3];
        c4 = cn;

        uint4 bc; bc.x = pkh(c4[0], c4[1]); bc.y = pkh(c4[2], c4[3]); bc.z = 0u; bc.w = 0u;
        f16x8 bcf = frg(bc);
        cq4 = mfma16(Qf, bcf, zero4);

        float res2 = 0.f, ds2 = 0.f;
        f32x4 pja0 = zero4, pja1 = zero4;
#pragma unroll
        for (int qi = 0; qi < 6; ++qi) {
            const int q = QB + qi;
            const int m = q >> 2;
            const hv2 bmax2 = (m == 0) ? bmax2h0 : (m == 1) ? bmax2h1 : bmax2h2;
            const hv2 bmin2 = (m == 0) ? bmin2h0 : (m == 1) ? bmin2h1 : bmin2h2;
            f32x4 ua = mfma16(frg(AF1((2*q)*64 + l)), bcf, zero4);
            f32x4 ub = mfma16(frg(AF1((2*q+1)*64 + l)), bcf, zero4);
            hv2 ua01 = pkh2(ua[0], ua[1]), ua23 = pkh2(ua[2], ua[3]);
            hv2 ub01 = pkh2(ub[0], ub[1]), ub23 = pkh2(ub[2], ub[3]);
            hv2 ra2 = z2, da2 = z2;
            hv2 h2a0, h2a1, h2b0, h2b1;
            CLIPN(ua01, h2a0, 2*qi, 0)   CLIPN(ua23, h2a1, 2*qi, 1)
            CLIPN(ub01, h2b0, 2*qi+1, 0) CLIPN(ub23, h2b1, 2*qi+1, 1)
            res2 += (float)ra2[0] + (float)ra2[1];
            ds2  += (float)da2[0] + (float)da2[1];
            uint4 bh;
            bh.x = h2u(h2a0); bh.y = h2u(h2a1); bh.z = h2u(h2b0); bh.w = h2u(h2b1);
            if (qi & 1) pja1 = mfma16(frg(Af2[q*64 + l]), frg(bh), pja1);
            else        pja0 = mfma16(frg(Af2[q*64 + l]), frg(bh), pja0);
        }
        f32x4 pjp = pja0 + pja1;

        // ---- cross-half exchange (double-buffered, 1 barrier/iter) ----
        const int buf = (it + 1) & 1;
        xch[buf][tile][half][ch][0][l] = pjp[0];
        xch[buf][tile][half][ch][1][l] = pjp[1];
        xch[buf][tile][half][ch][2][l] = pjp[2];
        xch[buf][tile][half][ch][3][l] = pjp[3];
        xch[buf][tile][half][ch][4][l] = res2;
        xch[buf][tile][half][ch][5][l] = ds2;
        __syncthreads();
        const int oh = 1 - half;
        pj4[0] = pjp[0] + xch[buf][tile][oh][ch][0][l];
        pj4[1] = pjp[1] + xch[buf][tile][oh][ch][1][l];
        pj4[2] = pjp[2] + xch[buf][tile][oh][ch][2][l];
        pj4[3] = pjp[3] + xch[buf][tile][oh][ch][3][l];
        res2 += xch[buf][tile][oh][ch][4][l];
        ds2  += xch[buf][tile][oh][ch][5][l];

        float pj2 = pj4[0]*pj4[0] + pj4[1]*pj4[1] + pj4[2]*pj4[2] + pj4[3]*pj4[3];
        L4 = L4 - pj4;

        // all-reduce the 4 scalars over the 4 lane-groups (same batch row)
        res2  += __shfl_xor(res2, 16, 64);  res2  += __shfl_xor(res2, 32, 64);
        ds2   += __shfl_xor(ds2, 16, 64);   ds2   += __shfl_xor(ds2, 32, 64);
        cdel2 += __shfl_xor(cdel2, 16, 64); cdel2 += __shfl_xor(cdel2, 32, 64);
        pj2   += __shfl_xor(pj2, 16, 64);   pj2   += __shfl_xor(pj2, 32, 64);

        if (g == 0 && half == 0) {
            res_st[it][tile][ch][l15] = sqrtf(res2);
            fix_st[it][tile][ch][l15] = sqrtf(pj2) + sqrtf(ds2) + sqrtf(cdel2);
        }
    }

    // ---- outputs ----
    if (half == 0) {
        float4 o; o.x = c4[0]; o.y = c4[1]; o.z = c4[2]; o.w = c4[3];
        *(float4*)(out + ch*(BATCH*NVARS) + row*16 + 4*g) = o;
    }
    __syncthreads();
    if (tid < 480) {
        int it = tid / 32, r = tid % 32;
        int tl = r >> 4, rr = r & 15;
        out[OUT_PST + it*BATCH + blockIdx.x*32 + r] =
            res_st[it][tl][0][rr] + res_st[it][tl][1][rr] + res_st[it][tl][2][rr];
        out[OUT_FST + it*BATCH + blockIdx.x*32 + r] =
            fix_st[it][tl][0][rr] + fix_st[it][tl][1][rr] + fix_st[it][tl][2][rr];
    }
    if (tid >= 512 && tid < 544) {
        int r = tid - 512;
        int tl = r >> 4, rr = r & 15;
        float s = 0.f;
        for (int it = 0; it < ITERS; ++it)
            s += res_st[it][tl][0][rr] + res_st[it][tl][1][rr] + res_st[it][tl][2][rr];
        out[OUT_ACCP + blockIdx.x*32 + r] = s * (1.f / 15.f);
    } else if (tid >= 544 && tid < 576) {
        int r = tid - 544;
        int tl = r >> 4, rr = r & 15;
        float s = 0.f;
        for (int it = 0; it < ITERS; ++it)
            s += fix_st[it][tl][0][rr] + fix_st[it][tl][1][rr] + fix_st[it][tl][2][rr];
        out[OUT_ACCF + blockIdx.x*32 + r] = s * (1.f / 15.f);
    }
}

extern "C" void kernel_launch(void* const* d_in, const int* in_sizes, int n_in,
                              void* d_out, int out_size, void* d_ws, size_t ws_size,
                              hipStream_t stream)
{
    const float* P    = (const float*)d_in[0];
    const float* Pdm  = (const float*)d_in[1];
    const float* Pddm = (const float*)d_in[2];
    const float* lamv = (const float*)d_in[3];
    const float* lamp = (const float*)d_in[4];
    const float* lamr = (const float*)d_in[5];
    const float* cinv = (const float*)d_in[6];
    const float* cinp = (const float*)d_in[7];
    const float* cinr = (const float*)d_in[8];
    const float* beqv = (const float*)d_in[9];
    const float* beqp = (const float*)d_in[10];
    const float* beqr = (const float*)d_in[11];
    const float* c0v  = (const float*)d_in[12];
    const float* c0p  = (const float*)d_in[13];
    const float* c0r  = (const float*)d_in[14];
    float* ws = (float*)d_ws;

    prep_kernel<<<1, 648, 0, stream>>>(P, Pdm, Pddm, ws);
    solve_kernel<<<256, 768, 0, stream>>>(P, Pdm, Pddm,
        lamv, lamp, lamr, cinv, cinp, cinr,
        beqv, beqp, beqr, c0v, c0p, c0r,
        (float*)d_out, ws);
}